// Round 3
// baseline (535.756 us; speedup 1.0000x reference)
//
#include <hip/hip_runtime.h>

// SHGR kNN head: cosine distance, top-16, inverse-distance weighted target average.
// B=2048, N=100000, D=128, T=8, k=16.
//
// Pipeline:
//   1. norm_rows_k: L2-normalize supports & queries -> bf16 (ushort bits) in ws.
//   2. score_select_k (dbuf async staging, XCD-sliced):
//        pass 1: bf16 MFMA, per-(query,chunk) max -> cm (LDS).
//        thr[q] = 16th largest chunk-max (bitonic-64)  [provably <= true 16th score]
//        pass 2: recompute scores (bitwise identical), append scores >= thr to a
//                pooled per-query GLOBAL candidate list (atomic counter).
//   3. merge_refine_k: per query, approx top-32 of ~615 pooled candidates -> exact
//      (f64) refine (4 at a time) -> exact top-16 (bitonic) -> weights -> out.

#define NSLICES 32
#define CN 64      // supports per chunk
#define BQ 128     // queries per block
#define CMP 52     // cm row stride (ushorts), nch<=49
#define GCAP_MAX 1024
#define SL 16      // merge: candidate slots per lane (GCAP_MAX/64)

typedef __bf16 bf16x8 __attribute__((ext_vector_type(8)));
typedef float f32x4 __attribute__((ext_vector_type(4)));

__device__ __forceinline__ ushort f2bf(float f) {
  unsigned u = __float_as_uint(f);
  unsigned r = (u + 0x7FFFu + ((u >> 16) & 1u)) >> 16;  // RNE
  return (ushort)r;
}

// Full-wave bitonic sort, ascending in (v, i) lexicographic.
__device__ __forceinline__ void bitonic64(float& v, unsigned& i, int lane) {
  #pragma unroll
  for (int k = 2; k <= 64; k <<= 1) {
    #pragma unroll
    for (int j = k >> 1; j > 0; j >>= 1) {
      float pv = __shfl_xor(v, j);
      unsigned pi = (unsigned)__shfl_xor((int)i, j);
      bool up = ((lane & k) == 0);
      bool lower = ((lane & j) == 0);
      bool gt = (v > pv) || (v == pv && i > pi);
      bool keep = (up == lower) ? !gt : gt;
      if (!keep) { v = pv; i = pi; }
    }
  }
}

// Normalize rows of x [nrows][128] -> bf16 bits. One wave per row.
__global__ __launch_bounds__(256) void norm_rows_k(const float* __restrict__ x,
                                                   ushort* __restrict__ xb,
                                                   int nrows) {
  int row = blockIdx.x * 4 + (threadIdx.x >> 6);
  int lane = threadIdx.x & 63;
  if (row >= nrows) return;
  float2 v = *reinterpret_cast<const float2*>(x + (size_t)row * 128 + lane * 2);
  float ss = v.x * v.x + v.y * v.y;
  #pragma unroll
  for (int o = 1; o < 64; o <<= 1) ss += __shfl_xor(ss, o);
  float inv = 1.0f / fmaxf(sqrtf(ss), 1e-12f);
  ushort2 h = make_ushort2(f2bf(v.x * inv), f2bf(v.y * inv));
  *reinterpret_cast<ushort2*>(xb + (size_t)row * 128 + lane * 2) = h;
}

// Async-stage one 64x128 bf16 chunk (16KB) into LDS. Dest is LINEAR in lane
// order (global_load_lds requirement); the XOR swizzle is applied by permuting
// the per-lane GLOBAL source block (rule: linear dest + inverse-swz source +
// swz on read). 256 threads x 4 issues x 16B.
__device__ __forceinline__ void stage_chunk(const ushort* __restrict__ sn,
                                            ushort* stbuf, int cb, int s1,
                                            int tid) {
  #pragma unroll
  for (int r = 0; r < 4; ++r) {
    int o = (r << 12) + tid * 16;   // dest byte offset in 16KB tile
    int row = o >> 8;               // 0..63
    int dj = (o >> 4) & 15;         // dest 16B block in row
    int sj = dj ^ (row & 7);        // source 16B block (swizzle inverse)
    int srow = min(cb + row, s1 - 1);
    __builtin_amdgcn_global_load_lds(
        (const unsigned int*)(sn + (size_t)srow * 128 + sj * 8),
        (unsigned int*)(stbuf + (o >> 1)), 16, 0, 0);
  }
}

// Two-pass threshold select. 1-D grid of (B/BQ)*NSLICES blocks, XCD-decoded so
// each XCD owns 4 slices (L2 working set 3.2MB < 4MB).
__global__ __launch_bounds__(256) void score_select_k(
    const ushort* __restrict__ qn, const ushort* __restrict__ sn,
    unsigned* __restrict__ gcnt, float2* __restrict__ gcand,
    int N, int gcap) {
  __shared__ ushort st[2][64 * 128];  // 32KB double-buffered chunk
  __shared__ ushort cm[BQ * CMP];     // 13.3KB chunk maxes (bf16 bits, down-rounded)
  __shared__ float thr_l[BQ];

  const int tid = threadIdx.x;
  const int w = tid >> 6;
  const int lane = tid & 63;
  const int g = lane >> 4;
  const int m = lane & 15;

  const int L = blockIdx.x;           // 512 = 8 xcd * (16 qtile * 4 slice)
  const int xcd = L & 7;
  const int i6 = L >> 3;              // 0..63
  const int qtile = i6 & 15;
  const int slice = (xcd << 2) | (i6 >> 4);

  const int qbase = qtile * BQ;
  const int SLICE = (N + NSLICES - 1) / NSLICES;
  const int s0 = slice * SLICE;
  const int s1 = min(N, s0 + SLICE);
  const int nch = (s1 - s0 + CN - 1) / CN;  // 49

  // prefetch chunk 0 under the A-fragment loads
  stage_chunk(sn, &st[0][0], s0, s1, tid);

  // A-fragments (queries): k = 32*t + 8*g + e, row = m. Same (lane,elem)->k map
  // is used for B, so any HW k-permutation cancels.
  bf16x8 afr[2][4];
  #pragma unroll
  for (int sub = 0; sub < 2; ++sub) {
    int qrow = qbase + w * 32 + sub * 16 + m;
    #pragma unroll
    for (int t = 0; t < 4; ++t)
      afr[sub][t] = *reinterpret_cast<const bf16x8*>(qn + (size_t)qrow * 128 + t * 32 + g * 8);
  }
  __syncthreads();

  // ---------------- pass 1: per-(query,chunk) maxes ----------------
  int buf = 0;
  for (int ch = 0; ch < nch; ++ch) {
    if (ch + 1 < nch) stage_chunk(sn, &st[buf ^ 1][0], s0 + (ch + 1) * CN, s1, tid);
    const ushort* stc = &st[buf][0];
    float rmax[2][4];
    #pragma unroll
    for (int sub = 0; sub < 2; ++sub)
      #pragma unroll
      for (int e = 0; e < 4; ++e) rmax[sub][e] = -3.0e38f;
    #pragma unroll
    for (int ct = 0; ct < 4; ++ct) {
      const int srow = ct * 16 + m;
      f32x4 a0 = {0.f, 0.f, 0.f, 0.f}, a1 = {0.f, 0.f, 0.f, 0.f};
      #pragma unroll
      for (int t = 0; t < 4; ++t) {
        int cj = (4 * t + g) ^ (srow & 7);
        bf16x8 bfr = *reinterpret_cast<const bf16x8*>(&stc[srow * 128 + cj * 8]);
        a0 = __builtin_amdgcn_mfma_f32_16x16x32_bf16(afr[0][t], bfr, a0, 0, 0, 0);
        a1 = __builtin_amdgcn_mfma_f32_16x16x32_bf16(afr[1][t], bfr, a1, 0, 0, 0);
      }
      #pragma unroll
      for (int e = 0; e < 4; ++e) {
        rmax[0][e] = fmaxf(rmax[0][e], a0[e]);
        rmax[1][e] = fmaxf(rmax[1][e], a1[e]);
      }
    }
    #pragma unroll
    for (int sub = 0; sub < 2; ++sub)
      #pragma unroll
      for (int e = 0; e < 4; ++e) {
        float v = rmax[sub][e];
        #pragma unroll
        for (int o = 1; o < 16; o <<= 1) v = fmaxf(v, __shfl_xor(v, o));
        rmax[sub][e] = v;
      }
    if (m == 0) {
      #pragma unroll
      for (int sub = 0; sub < 2; ++sub)
        #pragma unroll
        for (int e = 0; e < 4; ++e) {
          int row = w * 32 + sub * 16 + g * 4 + e;
          unsigned u = __float_as_uint(rmax[sub][e]);
          // round toward -inf: safe (threshold only ever lowered)
          cm[row * CMP + ch] = (ushort)((u >> 16) + (u >> 31));
        }
    }
    __syncthreads();
    buf ^= 1;
  }

  // prefetch pass-2 chunk 0; its latency hides under the threshold bitonics
  stage_chunk(sn, &st[0][0], s0, s1, tid);

  // ---------------- threshold: 16th largest chunk-max ----------------
  for (int qq = 0; qq < 32; ++qq) {
    int q = w * 32 + qq;
    float v = (lane < nch) ? __uint_as_float(((unsigned)cm[q * CMP + lane]) << 16) : -3.0e38f;
    unsigned ii = (unsigned)lane;
    bitonic64(v, ii, lane);
    float t = __shfl(v, 48);  // 16th largest
    if (lane == 0) thr_l[q] = t;
  }
  __syncthreads();  // thr_l visible; also drains the chunk-0 prefetch
  float thrv[2][4];
  #pragma unroll
  for (int sub = 0; sub < 2; ++sub)
    #pragma unroll
    for (int e = 0; e < 4; ++e)
      thrv[sub][e] = thr_l[w * 32 + sub * 16 + g * 4 + e];

  // ---------------- pass 2: filter -> pooled global candidates ----------------
  buf = 0;
  for (int ch = 0; ch < nch; ++ch) {
    const int cb = s0 + ch * CN;
    if (ch + 1 < nch) stage_chunk(sn, &st[buf ^ 1][0], cb + CN, s1, tid);
    const ushort* stc = &st[buf][0];
    const int vcols = min(CN, s1 - cb);
    #pragma unroll
    for (int ct = 0; ct < 4; ++ct) {
      const int srow = ct * 16 + m;
      f32x4 a0 = {0.f, 0.f, 0.f, 0.f}, a1 = {0.f, 0.f, 0.f, 0.f};
      #pragma unroll
      for (int t = 0; t < 4; ++t) {
        int cj = (4 * t + g) ^ (srow & 7);
        bf16x8 bfr = *reinterpret_cast<const bf16x8*>(&stc[srow * 128 + cj * 8]);
        a0 = __builtin_amdgcn_mfma_f32_16x16x32_bf16(afr[0][t], bfr, a0, 0, 0, 0);
        a1 = __builtin_amdgcn_mfma_f32_16x16x32_bf16(afr[1][t], bfr, a1, 0, 0, 0);
      }
      const int col = ct * 16 + m;
      if (col < vcols) {
        #pragma unroll
        for (int e = 0; e < 4; ++e) {
          if (a0[e] >= thrv[0][e]) {
            int qg = qbase + w * 32 + g * 4 + e;
            unsigned p = atomicAdd(&gcnt[qg], 1u);
            if (p < (unsigned)gcap)
              gcand[(size_t)qg * gcap + p] = make_float2(a0[e], __int_as_float(cb + col));
          }
          if (a1[e] >= thrv[1][e]) {
            int qg = qbase + w * 32 + 16 + g * 4 + e;
            unsigned p = atomicAdd(&gcnt[qg], 1u);
            if (p < (unsigned)gcap)
              gcand[(size_t)qg * gcap + p] = make_float2(a1[e], __int_as_float(cb + col));
          }
        }
      }
    }
    __syncthreads();
    buf ^= 1;
  }
}

// One wave per query: approx top-32 of pooled candidates -> exact refine (f64,
// 4 candidates concurrently in 16-lane groups) -> exact top-16 (bitonic, tie by
// lower index) -> weights -> gather targets -> out.
__global__ __launch_bounds__(64) void merge_refine_k(
    const float* __restrict__ query, const float* __restrict__ supports,
    const float* __restrict__ targets, const unsigned* __restrict__ gcnt,
    const float2* __restrict__ gcand, float* __restrict__ out, int gcap) {
  const int q = blockIdx.x;
  const int lane = threadIdx.x;
  __shared__ float qh_s[128];
  __shared__ float darr[32];
  __shared__ int iarr[32];

  int cnt = (int)min(gcnt[q], (unsigned)gcap);
  float2 c[SL];
  #pragma unroll
  for (int i = 0; i < SL; ++i) {
    int slot = lane + (i << 6);
    c[i] = (slot < cnt) ? gcand[(size_t)q * gcap + slot]
                        : make_float2(-3.0e38f, __int_as_float(0));
  }

  // qhat (f32 values, f64-accumulated norm)
  float2 qv = *reinterpret_cast<const float2*>(query + (size_t)q * 128 + lane * 2);
  double qss = (double)qv.x * qv.x + (double)qv.y * qv.y;
  #pragma unroll
  for (int o = 1; o < 64; o <<= 1) qss += __shfl_xor(qss, o);
  float qn1 = fmaxf((float)sqrt(qss), 1e-12f);
  qh_s[lane * 2] = qv.x / qn1;
  qh_s[lane * 2 + 1] = qv.y / qn1;

  // approx top-32 by repeated wave-argmax
  int rsidx = 0;  // lane it<32 holds selected support idx
  for (int it = 0; it < 32; ++it) {
    float bv = -3.0e38f;
    int bs = lane << 4;
    #pragma unroll
    for (int i = 0; i < SL; ++i)
      if (c[i].x > bv) { bv = c[i].x; bs = (lane << 4) | i; }
    #pragma unroll
    for (int o = 1; o < 64; o <<= 1) {
      float ov = __shfl_xor(bv, o);
      int os = __shfl_xor(bs, o);
      if (ov > bv || (ov == bv && os < bs)) { bv = ov; bs = os; }
    }
    int widx = 0;
    if ((bs >> 4) == lane) {
      #pragma unroll
      for (int i = 0; i < SL; ++i)
        if (i == (bs & 15)) { widx = __float_as_int(c[i].y); c[i].x = -3.0e38f; }
    }
    widx = __shfl(widx, bs >> 4);
    if (lane == it) rsidx = widx;
  }
  __syncthreads();  // qh_s visible

  // exact refine, 4 candidates at a time (16-lane groups, 8 dims/lane)
  const int g16 = lane >> 4, m16 = lane & 15;
  float qh[8];
  #pragma unroll
  for (int d = 0; d < 8; ++d) qh[d] = qh_s[m16 * 8 + d];
  #pragma unroll
  for (int b = 0; b < 8; ++b) {
    int cc = b * 4 + g16;
    int sidx = __shfl(rsidx, cc);
    float4 sa = *reinterpret_cast<const float4*>(supports + (size_t)sidx * 128 + m16 * 8);
    float4 sb = *reinterpret_cast<const float4*>(supports + (size_t)sidx * 128 + m16 * 8 + 4);
    float sv[8] = {sa.x, sa.y, sa.z, sa.w, sb.x, sb.y, sb.z, sb.w};
    double ss = 0.0, dt = 0.0;
    #pragma unroll
    for (int d = 0; d < 8; ++d) {
      ss += (double)sv[d] * sv[d];
      dt += (double)qh[d] * sv[d];
    }
    #pragma unroll
    for (int o = 1; o < 16; o <<= 1) {
      ss += __shfl_xor(ss, o);
      dt += __shfl_xor(dt, o);
    }
    if (m16 == 0) {
      float sn1 = fmaxf((float)sqrt(ss), 1e-12f);
      darr[cc] = (float)(1.0 - dt / (double)sn1);
      iarr[cc] = sidx;
    }
  }
  __syncthreads();

  float dv = (lane < 32) ? darr[lane] : 3.0e38f;
  unsigned di = (lane < 32) ? (unsigned)iarr[lane] : 0xFFFFFFFFu;
  bitonic64(dv, di, lane);  // ascending (d, idx): lanes 0..15 = top-16, stable ties

  float wv = (lane < 16) ? 1.0f / (dv + 1e-8f) : 0.0f;
  float wsum = wv;
  #pragma unroll
  for (int o = 1; o < 64; o <<= 1) wsum += __shfl_xor(wsum, o);
  float acc[8];
  #pragma unroll
  for (int t = 0; t < 8; ++t) acc[t] = 0.f;
  if (lane < 16) {
    float wn = wv / wsum;
    const float* tp = targets + (size_t)di * 8;
    #pragma unroll
    for (int t = 0; t < 8; ++t) acc[t] = wn * tp[t];
  }
  #pragma unroll
  for (int o = 1; o < 16; o <<= 1) {
    #pragma unroll
    for (int t = 0; t < 8; ++t) acc[t] += __shfl_xor(acc[t], o);
  }
  if (lane == 0) {
    #pragma unroll
    for (int t = 0; t < 8; ++t) out[(size_t)q * 8 + t] = acc[t];
  }
}

extern "C" void kernel_launch(void* const* d_in, const int* in_sizes, int n_in,
                              void* d_out, int out_size, void* d_ws, size_t ws_size,
                              hipStream_t stream) {
  const float* query = (const float*)d_in[0];
  const float* supports = (const float*)d_in[1];
  const float* targets = (const float*)d_in[2];
  float* out = (float*)d_out;
  const int D = 128;
  const int B = in_sizes[0] / D;   // 2048
  const int N = in_sizes[1] / D;   // 100000

  char* ws = (char*)d_ws;
  size_t off = 0;
  ushort* sn = (ushort*)(ws + off); off += (size_t)N * D * 2;
  off = (off + 255) & ~(size_t)255;
  ushort* qn = (ushort*)(ws + off); off += (size_t)B * D * 2;
  off = (off + 255) & ~(size_t)255;
  unsigned* gcnt = (unsigned*)(ws + off); off += (size_t)B * 4;
  off = (off + 255) & ~(size_t)255;
  float2* gcand = (float2*)(ws + off);
  if (off >= ws_size) return;
  size_t avail = ws_size - off;
  int gcap = (int)((avail / ((size_t)B * sizeof(float2))) < (size_t)GCAP_MAX
                       ? (avail / ((size_t)B * sizeof(float2)))
                       : (size_t)GCAP_MAX);
  if (gcap < 16) return;

  hipMemsetAsync(gcnt, 0, (size_t)B * 4, stream);
  hipLaunchKernelGGL(norm_rows_k, dim3((N + 3) / 4), dim3(256), 0, stream, supports, sn, N);
  hipLaunchKernelGGL(norm_rows_k, dim3((B + 3) / 4), dim3(256), 0, stream, query, qn, B);
  int nblk = (B / BQ) * NSLICES;  // 512
  hipLaunchKernelGGL(score_select_k, dim3(nblk), dim3(256), 0, stream, qn, sn, gcnt, gcand, N, gcap);
  hipLaunchKernelGGL(merge_refine_k, dim3(B), dim3(64), 0, stream, query, supports, targets, gcnt, gcand, out, gcap);
}

// Round 4
// 377.124 us; speedup vs baseline: 1.4206x; 1.4206x over previous
//
#include <hip/hip_runtime.h>

// SHGR kNN head: cosine distance, top-16, inverse-distance weighted target average.
// B=2048, N=100000, D=128, T=8, k=16.
//
// Pipeline:
//   1. norm_rows_k: L2-normalize supports & queries -> bf16 (ushort bits) in ws.
//   2. score_select_k (async dbuf staging, XCD-sliced, LDS candidate collection):
//        pass 1: bf16 MFMA, per-(query,chunk) max -> cm (LDS, bf16 rounded down).
//        thr[q] = 16th largest chunk-max (bitonic-64)  [provably <= true 16th score]
//        pass 2: recompute scores (bitwise identical), append scores >= thr to a
//                packed 4B LDS candidate buffer (LDS atomics), final bitonic-64
//                per query -> per-slice top-16 -> cand (coalesced 128B).
//   3. merge_refine_k: per query, approx top-32 of 512 candidates -> exact (f64)
//      refine (4 at a time) -> exact top-16 (bitonic) -> weights -> out.

#define NSLICES 32
#define CN 64      // supports per chunk
#define BQ 128     // queries per block
#define CMP 52     // cm row stride (ushorts), nch<=49
#define CAP 48     // candidates per (query,slice); expected ~19, no overflow observed

typedef __bf16 bf16x8 __attribute__((ext_vector_type(8)));
typedef float f32x4 __attribute__((ext_vector_type(4)));

__device__ __forceinline__ ushort f2bf(float f) {
  unsigned u = __float_as_uint(f);
  unsigned r = (u + 0x7FFFu + ((u >> 16) & 1u)) >> 16;  // RNE (monotone)
  return (ushort)r;
}

// bf16 bits -> order-preserving u16 key (and back).
__device__ __forceinline__ unsigned bf2key(ushort b) {
  return (unsigned)(b ^ ((b & 0x8000u) ? 0xFFFFu : 0x8000u));
}
__device__ __forceinline__ ushort key2bf(unsigned k) {
  return (ushort)((k & 0x8000u) ? (k ^ 0x8000u) : (k ^ 0xFFFFu));
}

// Full-wave bitonic sort, ascending in (v, i) lexicographic (floats).
__device__ __forceinline__ void bitonic64(float& v, unsigned& i, int lane) {
  #pragma unroll
  for (int k = 2; k <= 64; k <<= 1) {
    #pragma unroll
    for (int j = k >> 1; j > 0; j >>= 1) {
      float pv = __shfl_xor(v, j);
      unsigned pi = (unsigned)__shfl_xor((int)i, j);
      bool up = ((lane & k) == 0);
      bool lower = ((lane & j) == 0);
      bool gt = (v > pv) || (v == pv && i > pi);
      bool keep = (up == lower) ? !gt : gt;
      if (!keep) { v = pv; i = pi; }
    }
  }
}

// Full-wave bitonic sort on u32 keys, ascending.
__device__ __forceinline__ void bitonic64u(unsigned& v, int lane) {
  #pragma unroll
  for (int k = 2; k <= 64; k <<= 1) {
    #pragma unroll
    for (int j = k >> 1; j > 0; j >>= 1) {
      unsigned pv = (unsigned)__shfl_xor((int)v, j);
      bool up = ((lane & k) == 0);
      bool lower = ((lane & j) == 0);
      bool keep = ((up == lower) ? !(v > pv) : (v > pv));
      if (!keep) v = pv;
    }
  }
}

// Normalize rows of x [nrows][128] -> bf16 bits. One wave per row.
__global__ __launch_bounds__(256) void norm_rows_k(const float* __restrict__ x,
                                                   ushort* __restrict__ xb,
                                                   int nrows) {
  int row = blockIdx.x * 4 + (threadIdx.x >> 6);
  int lane = threadIdx.x & 63;
  if (row >= nrows) return;
  float2 v = *reinterpret_cast<const float2*>(x + (size_t)row * 128 + lane * 2);
  float ss = v.x * v.x + v.y * v.y;
  #pragma unroll
  for (int o = 1; o < 64; o <<= 1) ss += __shfl_xor(ss, o);
  float inv = 1.0f / fmaxf(sqrtf(ss), 1e-12f);
  ushort2 h = make_ushort2(f2bf(v.x * inv), f2bf(v.y * inv));
  *reinterpret_cast<ushort2*>(xb + (size_t)row * 128 + lane * 2) = h;
}

// Async-stage one 64x128 bf16 chunk (16KB) into LDS. Dest is LINEAR in lane
// order (global_load_lds requirement); the XOR swizzle is applied by permuting
// the per-lane GLOBAL source block (linear dest + inverse-swz source + swz read).
__device__ __forceinline__ void stage_chunk(const ushort* __restrict__ sn,
                                            ushort* stbuf, int cb, int s1,
                                            int tid) {
  #pragma unroll
  for (int r = 0; r < 4; ++r) {
    int o = (r << 12) + tid * 16;   // dest byte offset in 16KB tile
    int row = o >> 8;               // 0..63
    int dj = (o >> 4) & 15;         // dest 16B block in row
    int sj = dj ^ (row & 7);        // source 16B block (swizzle inverse)
    int srow = min(cb + row, s1 - 1);
    __builtin_amdgcn_global_load_lds(
        (const unsigned int*)(sn + (size_t)srow * 128 + sj * 8),
        (unsigned int*)(stbuf + (o >> 1)), 16, 0, 0);
  }
}

// Two-pass threshold select. 1-D grid of 512 blocks, XCD-decoded so each XCD
// owns 4 slices (per-XCD L2 working set 3.2MB < 4MB).
__global__ __launch_bounds__(256) void score_select_k(
    const ushort* __restrict__ qn, const ushort* __restrict__ sn,
    float2* __restrict__ cand, int N) {
  __shared__ ushort st[2][64 * 128];   // 32KB double-buffered chunk
  __shared__ ushort cm[BQ * CMP];      // 13.3KB chunk maxes (bf16, rounded down)
  __shared__ unsigned cbuf[BQ * CAP];  // 24KB packed candidates
  __shared__ unsigned cnt_l[BQ];
  __shared__ float thr_l[BQ];

  const int tid = threadIdx.x;
  const int w = tid >> 6;
  const int lane = tid & 63;
  const int g = lane >> 4;
  const int m = lane & 15;

  const int L = blockIdx.x;            // 512 = 8 xcd * (16 qtile * 4 slice)
  const int xcd = L & 7;
  const int i6 = L >> 3;               // 0..63
  const int qtile = i6 & 15;
  const int slice = (xcd << 2) | (i6 >> 4);

  const int qbase = qtile * BQ;
  const int SLICE = (N + NSLICES - 1) / NSLICES;
  const int s0 = slice * SLICE;
  const int s1 = min(N, s0 + SLICE);
  const int nch = (s1 - s0 + CN - 1) / CN;  // 49

  // prefetch chunk 0 under the A-fragment loads
  stage_chunk(sn, &st[0][0], s0, s1, tid);

  // A-fragments (queries): k = 32*t + 8*g + e, row = m. Same (lane,elem)->k map
  // is used for B, so any HW k-permutation cancels.
  bf16x8 afr[2][4];
  #pragma unroll
  for (int sub = 0; sub < 2; ++sub) {
    int qrow = qbase + w * 32 + sub * 16 + m;
    #pragma unroll
    for (int t = 0; t < 4; ++t)
      afr[sub][t] = *reinterpret_cast<const bf16x8*>(qn + (size_t)qrow * 128 + t * 32 + g * 8);
  }
  if (tid < BQ) cnt_l[tid] = 0;
  __syncthreads();

  // ---------------- pass 1: per-(query,chunk) maxes ----------------
  int buf = 0;
  for (int ch = 0; ch < nch; ++ch) {
    if (ch + 1 < nch) stage_chunk(sn, &st[buf ^ 1][0], s0 + (ch + 1) * CN, s1, tid);
    const ushort* stc = &st[buf][0];
    float rmax[2][4];
    #pragma unroll
    for (int sub = 0; sub < 2; ++sub)
      #pragma unroll
      for (int e = 0; e < 4; ++e) rmax[sub][e] = -3.0e38f;
    #pragma unroll
    for (int ct = 0; ct < 4; ++ct) {
      const int srow = ct * 16 + m;
      f32x4 a0 = {0.f, 0.f, 0.f, 0.f}, a1 = {0.f, 0.f, 0.f, 0.f};
      #pragma unroll
      for (int t = 0; t < 4; ++t) {
        int cj = (4 * t + g) ^ (srow & 7);
        bf16x8 bfr = *reinterpret_cast<const bf16x8*>(&stc[srow * 128 + cj * 8]);
        a0 = __builtin_amdgcn_mfma_f32_16x16x32_bf16(afr[0][t], bfr, a0, 0, 0, 0);
        a1 = __builtin_amdgcn_mfma_f32_16x16x32_bf16(afr[1][t], bfr, a1, 0, 0, 0);
      }
      #pragma unroll
      for (int e = 0; e < 4; ++e) {
        rmax[0][e] = fmaxf(rmax[0][e], a0[e]);
        rmax[1][e] = fmaxf(rmax[1][e], a1[e]);
      }
    }
    #pragma unroll
    for (int sub = 0; sub < 2; ++sub)
      #pragma unroll
      for (int e = 0; e < 4; ++e) {
        float v = rmax[sub][e];
        #pragma unroll
        for (int o = 1; o < 16; o <<= 1) v = fmaxf(v, __shfl_xor(v, o));
        rmax[sub][e] = v;
      }
    if (m == 0) {
      #pragma unroll
      for (int sub = 0; sub < 2; ++sub)
        #pragma unroll
        for (int e = 0; e < 4; ++e) {
          int row = w * 32 + sub * 16 + g * 4 + e;
          unsigned u = __float_as_uint(rmax[sub][e]);
          // round toward -inf: safe (threshold only ever lowered)
          cm[row * CMP + ch] = (ushort)((u >> 16) + (u >> 31));
        }
    }
    __syncthreads();
    buf ^= 1;
  }

  // prefetch pass-2 chunk 0; latency hides under the threshold bitonics
  stage_chunk(sn, &st[0][0], s0, s1, tid);

  // ---------------- threshold: 16th largest chunk-max ----------------
  for (int qq = 0; qq < 32; ++qq) {
    int q = w * 32 + qq;
    float v = (lane < nch) ? __uint_as_float(((unsigned)cm[q * CMP + lane]) << 16) : -3.0e38f;
    unsigned ii = (unsigned)lane;
    bitonic64(v, ii, lane);
    float t = __shfl(v, 48);  // 16th largest
    if (lane == 0) thr_l[q] = t;
  }
  __syncthreads();  // thr_l visible; also drains the chunk-0 prefetch
  float thrv[2][4];
  #pragma unroll
  for (int sub = 0; sub < 2; ++sub)
    #pragma unroll
    for (int e = 0; e < 4; ++e)
      thrv[sub][e] = thr_l[w * 32 + sub * 16 + g * 4 + e];

  // ---------------- pass 2: filter -> packed LDS candidates ----------------
  buf = 0;
  for (int ch = 0; ch < nch; ++ch) {
    const int cb = s0 + ch * CN;
    if (ch + 1 < nch) stage_chunk(sn, &st[buf ^ 1][0], cb + CN, s1, tid);
    const ushort* stc = &st[buf][0];
    const int vcols = min(CN, s1 - cb);
    #pragma unroll
    for (int ct = 0; ct < 4; ++ct) {
      const int srow = ct * 16 + m;
      f32x4 a0 = {0.f, 0.f, 0.f, 0.f}, a1 = {0.f, 0.f, 0.f, 0.f};
      #pragma unroll
      for (int t = 0; t < 4; ++t) {
        int cj = (4 * t + g) ^ (srow & 7);
        bf16x8 bfr = *reinterpret_cast<const bf16x8*>(&stc[srow * 128 + cj * 8]);
        a0 = __builtin_amdgcn_mfma_f32_16x16x32_bf16(afr[0][t], bfr, a0, 0, 0, 0);
        a1 = __builtin_amdgcn_mfma_f32_16x16x32_bf16(afr[1][t], bfr, a1, 0, 0, 0);
      }
      const int col = ct * 16 + m;
      if (col < vcols) {
        const int lidx = cb + col - s0;  // slice-local (<3125, fits 16b complement)
        #pragma unroll
        for (int e = 0; e < 4; ++e) {
          if (a0[e] >= thrv[0][e]) {
            int q = w * 32 + g * 4 + e;
            unsigned p = atomicAdd(&cnt_l[q], 1u);
            if (p < CAP)
              cbuf[q * CAP + p] = (bf2key(f2bf(a0[e])) << 16) | (unsigned)(lidx ^ 0xFFFF);
          }
          if (a1[e] >= thrv[1][e]) {
            int q = w * 32 + 16 + g * 4 + e;
            unsigned p = atomicAdd(&cnt_l[q], 1u);
            if (p < CAP)
              cbuf[q * CAP + p] = (bf2key(f2bf(a1[e])) << 16) | (unsigned)(lidx ^ 0xFFFF);
          }
        }
      }
    }
    __syncthreads();
    buf ^= 1;
  }

  // ---------------- final: per-query top-16 of packed candidates ----------------
  for (int qq = 0; qq < 32; ++qq) {
    int q = w * 32 + qq;
    unsigned mc = min(cnt_l[q], (unsigned)CAP);  // >=16 guaranteed by thr construction
    unsigned v = ((unsigned)lane < mc) ? cbuf[q * CAP + lane] : 0u;  // 0 sorts below all real keys
    bitonic64u(v, lane);
    if (lane >= 48) {
      float sc = __uint_as_float(((unsigned)key2bf(v >> 16)) << 16);
      int gidx = s0 + (int)((v & 0xFFFFu) ^ 0xFFFFu);
      cand[((size_t)(qbase + q) * NSLICES + slice) * 16 + (lane - 48)] =
          make_float2(sc, __int_as_float(gidx));
    }
  }
}

// One wave per query: approx top-32 of 512 candidates -> exact refine (f64,
// 4 candidates concurrently in 16-lane groups) -> exact top-16 (bitonic, tie by
// lower index) -> weights -> gather targets -> out.
__global__ __launch_bounds__(64) void merge_refine_k(
    const float* __restrict__ query, const float* __restrict__ supports,
    const float* __restrict__ targets, const float2* __restrict__ cand,
    float* __restrict__ out) {
  const int q = blockIdx.x;
  const int lane = threadIdx.x;
  __shared__ float qh_s[128];
  __shared__ float darr[32];
  __shared__ int iarr[32];

  float2 c[8];
  #pragma unroll
  for (int i = 0; i < 8; ++i) c[i] = cand[(size_t)q * (NSLICES * 16) + lane * 8 + i];

  // qhat (f32 values, f64-accumulated norm)
  float2 qv = *reinterpret_cast<const float2*>(query + (size_t)q * 128 + lane * 2);
  double qss = (double)qv.x * qv.x + (double)qv.y * qv.y;
  #pragma unroll
  for (int o = 1; o < 64; o <<= 1) qss += __shfl_xor(qss, o);
  float qn1 = fmaxf((float)sqrt(qss), 1e-12f);
  qh_s[lane * 2] = qv.x / qn1;
  qh_s[lane * 2 + 1] = qv.y / qn1;

  // approx top-32 by repeated wave-argmax
  int rsidx = 0;  // lane it<32 holds selected support idx
  for (int it = 0; it < 32; ++it) {
    float bv = -3.0e38f;
    int bs = lane << 3;
    #pragma unroll
    for (int i = 0; i < 8; ++i)
      if (c[i].x > bv) { bv = c[i].x; bs = (lane << 3) | i; }
    #pragma unroll
    for (int o = 1; o < 64; o <<= 1) {
      float ov = __shfl_xor(bv, o);
      int os = __shfl_xor(bs, o);
      if (ov > bv || (ov == bv && os < bs)) { bv = ov; bs = os; }
    }
    int widx = 0;
    if ((bs >> 3) == lane) {
      #pragma unroll
      for (int i = 0; i < 8; ++i)
        if (i == (bs & 7)) { widx = __float_as_int(c[i].y); c[i].x = -3.0e38f; }
    }
    widx = __shfl(widx, bs >> 3);
    if (lane == it) rsidx = widx;
  }
  __syncthreads();  // qh_s visible

  // exact refine, 4 candidates at a time (16-lane groups, 8 dims/lane)
  const int g16 = lane >> 4, m16 = lane & 15;
  float qh[8];
  #pragma unroll
  for (int d = 0; d < 8; ++d) qh[d] = qh_s[m16 * 8 + d];
  #pragma unroll
  for (int b = 0; b < 8; ++b) {
    int cc = b * 4 + g16;
    int sidx = __shfl(rsidx, cc);
    float4 sa = *reinterpret_cast<const float4*>(supports + (size_t)sidx * 128 + m16 * 8);
    float4 sb = *reinterpret_cast<const float4*>(supports + (size_t)sidx * 128 + m16 * 8 + 4);
    float sv[8] = {sa.x, sa.y, sa.z, sa.w, sb.x, sb.y, sb.z, sb.w};
    double ss = 0.0, dt = 0.0;
    #pragma unroll
    for (int d = 0; d < 8; ++d) {
      ss += (double)sv[d] * sv[d];
      dt += (double)qh[d] * sv[d];
    }
    #pragma unroll
    for (int o = 1; o < 16; o <<= 1) {
      ss += __shfl_xor(ss, o);
      dt += __shfl_xor(dt, o);
    }
    if (m16 == 0) {
      float sn1 = fmaxf((float)sqrt(ss), 1e-12f);
      darr[cc] = (float)(1.0 - dt / (double)sn1);
      iarr[cc] = sidx;
    }
  }
  __syncthreads();

  float dv = (lane < 32) ? darr[lane] : 3.0e38f;
  unsigned di = (lane < 32) ? (unsigned)iarr[lane] : 0xFFFFFFFFu;
  bitonic64(dv, di, lane);  // ascending (d, idx): lanes 0..15 = top-16, stable ties

  float wv = (lane < 16) ? 1.0f / (dv + 1e-8f) : 0.0f;
  float wsum = wv;
  #pragma unroll
  for (int o = 1; o < 64; o <<= 1) wsum += __shfl_xor(wsum, o);
  float acc[8];
  #pragma unroll
  for (int t = 0; t < 8; ++t) acc[t] = 0.f;
  if (lane < 16) {
    float wn = wv / wsum;
    const float* tp = targets + (size_t)di * 8;
    #pragma unroll
    for (int t = 0; t < 8; ++t) acc[t] = wn * tp[t];
  }
  #pragma unroll
  for (int o = 1; o < 16; o <<= 1) {
    #pragma unroll
    for (int t = 0; t < 8; ++t) acc[t] += __shfl_xor(acc[t], o);
  }
  if (lane == 0) {
    #pragma unroll
    for (int t = 0; t < 8; ++t) out[(size_t)q * 8 + t] = acc[t];
  }
}

extern "C" void kernel_launch(void* const* d_in, const int* in_sizes, int n_in,
                              void* d_out, int out_size, void* d_ws, size_t ws_size,
                              hipStream_t stream) {
  const float* query = (const float*)d_in[0];
  const float* supports = (const float*)d_in[1];
  const float* targets = (const float*)d_in[2];
  float* out = (float*)d_out;
  const int D = 128;
  const int B = in_sizes[0] / D;   // 2048
  const int N = in_sizes[1] / D;   // 100000

  char* ws = (char*)d_ws;
  size_t off = 0;
  ushort* sn = (ushort*)(ws + off); off += (size_t)N * D * 2;
  off = (off + 255) & ~(size_t)255;
  ushort* qn = (ushort*)(ws + off); off += (size_t)B * D * 2;
  off = (off + 255) & ~(size_t)255;
  float2* cand = (float2*)(ws + off); off += (size_t)B * NSLICES * 16 * sizeof(float2);
  if (off > ws_size) return;

  hipLaunchKernelGGL(norm_rows_k, dim3((N + 3) / 4), dim3(256), 0, stream, supports, sn, N);
  hipLaunchKernelGGL(norm_rows_k, dim3((B + 3) / 4), dim3(256), 0, stream, query, qn, B);
  int nblk = (B / BQ) * NSLICES;  // 512
  hipLaunchKernelGGL(score_select_k, dim3(nblk), dim3(256), 0, stream, qn, sn, cand, N);
  hipLaunchKernelGGL(merge_refine_k, dim3(B), dim3(64), 0, stream, query, supports, targets, cand, out);
}

// Round 6
// 374.632 us; speedup vs baseline: 1.4301x; 1.0067x over previous
//
#include <hip/hip_runtime.h>

// SHGR kNN head: cosine distance, top-16, inverse-distance weighted target average.
// B=2048, N=100000, D=128, T=8, k=16.
//
// Pipeline:
//   1. norm_rows_k: L2-normalize supports & queries -> bf16 (ushort bits) in ws.
//   2. pass1_k: bf16 MFMA; per-(query, 16-col sub-chunk) max -> cm (global, bf16
//      down-rounded, packed [q/4][gs][q%4]).  LDS = 32KB staging only.
//   3. thr_k: thr[q] = (16th-largest of 6272 sub-maxes) - 0.013 margin, via
//      ballot-popcount radix select.  [16th submax <= true 16th score; margin
//      covers bf16 score error (<=2.5e-3 worst case) with 5x slack; tail math:
//      E[cands] = 16*exp(41*margin) ~ 27 per query]
//   4. pass2_k: per (qtile,slice) block: find hit subs (stored max >= thr),
//      batch 4 subs -> staged 64-row tile, recompute scores (bitwise identical
//      MFMA), emit scores >= thr to a per-query global list (cap 64).
//   5. merge_refine_k: per query, exact (f64) refine ALL ~27 candidates,
//      bitonic top-16 -> weights -> gather targets -> out.

#define NSLICES 32
#define CN 64
#define BQ 128
#define NSUB 196                 // subs per slice = 49 chunks * 4
#define NGS (NSLICES * NSUB)     // 6272 subs per query
#define QCAP 64                  // per-query candidate list; E=27, P(>64)~1e-9
#define THR_MARGIN 0.013f

typedef __bf16 bf16x8 __attribute__((ext_vector_type(8)));
typedef float f32x4 __attribute__((ext_vector_type(4)));

__device__ __forceinline__ ushort f2bf_rne(float f) {
  unsigned u = __float_as_uint(f);
  return (ushort)((u + 0x7FFFu + ((u >> 16) & 1u)) >> 16);
}
// round toward -inf in bf16 (stored max <= true max)
__device__ __forceinline__ ushort f2bf_down(float f) {
  unsigned u = __float_as_uint(f);
  return (ushort)((u >> 16) + (u >> 31));
}
__device__ __forceinline__ unsigned bf2key(ushort b) {
  return (unsigned)(b ^ ((b & 0x8000u) ? 0xFFFFu : 0x8000u));
}

// Full-wave bitonic sort, ascending in (v, i) lexicographic.
__device__ __forceinline__ void bitonic64(float& v, unsigned& i, int lane) {
  #pragma unroll
  for (int k = 2; k <= 64; k <<= 1) {
    #pragma unroll
    for (int j = k >> 1; j > 0; j >>= 1) {
      float pv = __shfl_xor(v, j);
      unsigned pi = (unsigned)__shfl_xor((int)i, j);
      bool up = ((lane & k) == 0);
      bool lower = ((lane & j) == 0);
      bool gt = (v > pv) || (v == pv && i > pi);
      bool keep = (up == lower) ? !gt : gt;
      if (!keep) { v = pv; i = pi; }
    }
  }
}

__global__ __launch_bounds__(256) void norm_rows_k(const float* __restrict__ x,
                                                   ushort* __restrict__ xb,
                                                   int nrows) {
  int row = blockIdx.x * 4 + (threadIdx.x >> 6);
  int lane = threadIdx.x & 63;
  if (row >= nrows) return;
  float2 v = *reinterpret_cast<const float2*>(x + (size_t)row * 128 + lane * 2);
  float ss = v.x * v.x + v.y * v.y;
  #pragma unroll
  for (int o = 1; o < 64; o <<= 1) ss += __shfl_xor(ss, o);
  float inv = 1.0f / fmaxf(sqrtf(ss), 1e-12f);
  ushort2 h = make_ushort2(f2bf_rne(v.x * inv), f2bf_rne(v.y * inv));
  *reinterpret_cast<ushort2*>(xb + (size_t)row * 128 + lane * 2) = h;
}

// Stage 64x128 bf16 chunk: linear LDS dest + inverse-swizzled global source.
__device__ __forceinline__ void stage_lin(const ushort* __restrict__ sn,
                                          ushort* dst, int cb, int s1, int tid) {
  #pragma unroll
  for (int r = 0; r < 4; ++r) {
    int o = (r << 12) + tid * 16;
    int row = o >> 8;
    int dj = (o >> 4) & 15;
    int sj = dj ^ (row & 7);
    int srow = min(cb + row, s1 - 1);
    __builtin_amdgcn_global_load_lds(
        (const unsigned int*)(sn + (size_t)srow * 128 + sj * 8),
        (unsigned int*)(dst + (o >> 1)), 16, 0, 0);
  }
}

// Stage a gathered batch of 4 sub-chunks (16 rows each) from slist.
__device__ __forceinline__ void stage_list(const ushort* __restrict__ sn,
                                           ushort* dst, const ushort* slist_b,
                                           int s0, int s1, int tid) {
  #pragma unroll
  for (int r = 0; r < 4; ++r) {
    int o = (r << 12) + tid * 16;
    int row = o >> 8;
    int dj = (o >> 4) & 15;
    int sj = dj ^ (row & 7);
    int sub = slist_b[row >> 4];
    int lrow = (sub == 0xFFFF) ? 0 : sub * 16 + (row & 15);
    int srow = min(s0 + lrow, s1 - 1);
    __builtin_amdgcn_global_load_lds(
        (const unsigned int*)(sn + (size_t)srow * 128 + sj * 8),
        (unsigned int*)(dst + (o >> 1)), 16, 0, 0);
  }
}

// Pass 1: sub-chunk maxes. 512 blocks XCD-decoded (4 slices/XCD, L2-local).
__global__ __launch_bounds__(256, 4) void pass1_k(
    const ushort* __restrict__ qn, const ushort* __restrict__ sn,
    ushort* __restrict__ cm, int N) {
  __shared__ ushort st[2][CN * 128];
  const int tid = threadIdx.x;
  const int w = tid >> 6, lane = tid & 63, g = lane >> 4, m = lane & 15;
  const int L = blockIdx.x;
  const int xcd = L & 7, i6 = L >> 3;
  const int qtile = i6 & 15;
  const int slice = (xcd << 2) | (i6 >> 4);
  const int qbase = qtile * BQ;
  const int SLICE = (N + NSLICES - 1) / NSLICES;
  const int s0 = slice * SLICE;
  const int s1 = min(N, s0 + SLICE);
  const int nch = (s1 - s0 + CN - 1) / CN;  // 49

  stage_lin(sn, &st[0][0], s0, s1, tid);

  // A-fragments: k = 32*t + 8*g + e, row = m (same map for B -> permutation cancels)
  bf16x8 afr[2][4];
  #pragma unroll
  for (int sub = 0; sub < 2; ++sub) {
    int qrow = qbase + w * 32 + sub * 16 + m;
    #pragma unroll
    for (int t = 0; t < 4; ++t)
      afr[sub][t] = *reinterpret_cast<const bf16x8*>(qn + (size_t)qrow * 128 + t * 32 + g * 8);
  }
  __syncthreads();

  int buf = 0;
  for (int ch = 0; ch < nch; ++ch) {
    if (ch + 1 < nch) stage_lin(sn, &st[buf ^ 1][0], s0 + (ch + 1) * CN, s1, tid);
    const ushort* stc = &st[buf][0];
    #pragma unroll
    for (int ct = 0; ct < 4; ++ct) {
      const int srow = ct * 16 + m;
      f32x4 a0 = {0.f, 0.f, 0.f, 0.f}, a1 = {0.f, 0.f, 0.f, 0.f};
      #pragma unroll
      for (int t = 0; t < 4; ++t) {
        int cj = (4 * t + g) ^ (srow & 7);
        bf16x8 bfr = *reinterpret_cast<const bf16x8*>(&stc[srow * 128 + cj * 8]);
        a0 = __builtin_amdgcn_mfma_f32_16x16x32_bf16(afr[0][t], bfr, a0, 0, 0, 0);
        a1 = __builtin_amdgcn_mfma_f32_16x16x32_bf16(afr[1][t], bfr, a1, 0, 0, 0);
      }
      // per-(query, sub-chunk) max over the 16 m-lanes
      float m0[4], m1[4];
      #pragma unroll
      for (int e = 0; e < 4; ++e) { m0[e] = a0[e]; m1[e] = a1[e]; }
      #pragma unroll
      for (int o = 1; o < 16; o <<= 1) {
        #pragma unroll
        for (int e = 0; e < 4; ++e) {
          m0[e] = fmaxf(m0[e], __shfl_xor(m0[e], o));
          m1[e] = fmaxf(m1[e], __shfl_xor(m1[e], o));
        }
      }
      if (m == 0) {
        int gs = slice * NSUB + ch * 4 + ct;
        int q0 = qbase + w * 32 + g * 4;       // sub 0 queries (q0..q0+3)
        int q1 = q0 + 16;                      // sub 1
        uint2 p0, p1;
        p0.x = (unsigned)f2bf_down(m0[0]) | ((unsigned)f2bf_down(m0[1]) << 16);
        p0.y = (unsigned)f2bf_down(m0[2]) | ((unsigned)f2bf_down(m0[3]) << 16);
        p1.x = (unsigned)f2bf_down(m1[0]) | ((unsigned)f2bf_down(m1[1]) << 16);
        p1.y = (unsigned)f2bf_down(m1[2]) | ((unsigned)f2bf_down(m1[3]) << 16);
        *reinterpret_cast<uint2*>(cm + ((size_t)(q0 >> 2) * NGS + gs) * 4) = p0;
        *reinterpret_cast<uint2*>(cm + ((size_t)(q1 >> 2) * NGS + gs) * 4) = p1;
      }
    }
    __syncthreads();
    buf ^= 1;
  }
}

// thr[q] = 16th-largest of the 6272 sub-maxes, minus margin. One wave per query.
__global__ __launch_bounds__(64) void thr_k(const ushort* __restrict__ cm,
                                            float* __restrict__ thr) {
  const int q = blockIdx.x, lane = threadIdx.x;
  const size_t base = (size_t)(q >> 2) * NGS * 4 + (q & 3);
  unsigned keys[49];
  #pragma unroll
  for (int j = 0; j < 49; ++j) {
    unsigned k0 = bf2key(cm[base + (size_t)(lane + 64 * (2 * j)) * 4]);
    unsigned k1 = bf2key(cm[base + (size_t)(lane + 64 * (2 * j + 1)) * 4]);
    keys[j] = k0 | (k1 << 16);
  }
  unsigned res = 0;
  for (int b = 15; b >= 0; --b) {
    unsigned t = res | (1u << b);
    int c = 0;
    #pragma unroll
    for (int j = 0; j < 49; ++j)
      c += (int)((keys[j] & 0xFFFFu) >= t) + (int)((keys[j] >> 16) >= t);
    #pragma unroll
    for (int o = 1; o < 64; o <<= 1) c += __shfl_xor(c, o);
    if (c >= 16) res = t;
  }
  if (lane == 0) {
    ushort b16 = (ushort)((res & 0x8000u) ? (res ^ 0x8000u) : (res ^ 0xFFFFu));
    thr[q] = __uint_as_float((unsigned)b16 << 16) - THR_MARGIN;
  }
}

// Pass 2: visit only hit subs (stored max >= thr), 4 per staged batch.
__global__ __launch_bounds__(256, 4) void pass2_k(
    const ushort* __restrict__ qn, const ushort* __restrict__ sn,
    const ushort* __restrict__ cm, const float* __restrict__ thr,
    unsigned* __restrict__ cnt, float2* __restrict__ candq, int N) {
  __shared__ ushort st[2][CN * 128];
  __shared__ float thr_l[BQ];
  __shared__ unsigned char hit[NSUB];
  __shared__ ushort slist[NSUB + 4];
  __shared__ int nhit_s;

  const int tid = threadIdx.x;
  const int w = tid >> 6, lane = tid & 63, g = lane >> 4, m = lane & 15;
  const int L = blockIdx.x;
  const int xcd = L & 7, i6 = L >> 3;
  const int qtile = i6 & 15;
  const int slice = (xcd << 2) | (i6 >> 4);
  const int qbase = qtile * BQ;
  const int SLICE = (N + NSLICES - 1) / NSLICES;
  const int s0 = slice * SLICE;
  const int s1 = min(N, s0 + SLICE);
  const int slen = s1 - s0;

  if (tid < BQ) thr_l[tid] = thr[qbase + tid];
  if (tid < NSUB) hit[tid] = 0;
  __syncthreads();

  // hit scan: thread (q = tid&127, parity = tid>>7) covers s = 2j+parity
  {
    int q = qbase + (tid & 127);
    int sh = tid >> 7;
    float tq = thr_l[tid & 127];
    size_t base = (size_t)(q >> 2) * NGS * 4 + (q & 3);
    for (int j = 0; j < 98; ++j) {
      int s = 2 * j + sh;
      ushort b = cm[base + (size_t)(slice * NSUB + s) * 4];
      if (__uint_as_float((unsigned)b << 16) >= tq) hit[s] = 1;
    }
  }
  __syncthreads();
  // compact hit subs (wave 0)
  if (tid < 64) {
    int total = 0;
    #pragma unroll
    for (int r = 0; r < 4; ++r) {
      int idx = r * 64 + tid;
      bool f = (idx < NSUB) && hit[idx];
      unsigned long long bm = __ballot(f);
      int pos = total + __popcll(bm & ((1ull << tid) - 1ull));
      if (f) slist[pos] = (ushort)idx;
      total += __popcll(bm);
    }
    if (tid == 0) {
      nhit_s = total;
      #pragma unroll
      for (int p = 0; p < 4; ++p) slist[total + p] = 0xFFFF;
    }
  }
  __syncthreads();
  const int nhit = nhit_s;
  if (nhit == 0) return;
  const int nb = (nhit + 3) >> 2;

  bf16x8 afr[2][4];
  #pragma unroll
  for (int sub = 0; sub < 2; ++sub) {
    int qrow = qbase + w * 32 + sub * 16 + m;
    #pragma unroll
    for (int t = 0; t < 4; ++t)
      afr[sub][t] = *reinterpret_cast<const bf16x8*>(qn + (size_t)qrow * 128 + t * 32 + g * 8);
  }
  float thrv[2][4];
  #pragma unroll
  for (int sub = 0; sub < 2; ++sub)
    #pragma unroll
    for (int e = 0; e < 4; ++e)
      thrv[sub][e] = thr_l[w * 32 + sub * 16 + g * 4 + e];

  stage_list(sn, &st[0][0], &slist[0], s0, s1, tid);
  __syncthreads();

  int buf = 0;
  for (int b = 0; b < nb; ++b) {
    if (b + 1 < nb) stage_list(sn, &st[buf ^ 1][0], &slist[(b + 1) * 4], s0, s1, tid);
    const ushort* stc = &st[buf][0];
    #pragma unroll
    for (int ct = 0; ct < 4; ++ct) {
      const int srow = ct * 16 + m;
      f32x4 a0 = {0.f, 0.f, 0.f, 0.f}, a1 = {0.f, 0.f, 0.f, 0.f};
      #pragma unroll
      for (int t = 0; t < 4; ++t) {
        int cj = (4 * t + g) ^ (srow & 7);
        bf16x8 bfr = *reinterpret_cast<const bf16x8*>(&stc[srow * 128 + cj * 8]);
        a0 = __builtin_amdgcn_mfma_f32_16x16x32_bf16(afr[0][t], bfr, a0, 0, 0, 0);
        a1 = __builtin_amdgcn_mfma_f32_16x16x32_bf16(afr[1][t], bfr, a1, 0, 0, 0);
      }
      int sub = slist[b * 4 + ct];
      if (sub != 0xFFFF) {
        int lcol = sub * 16 + m;       // slice-local support index of this column
        if (lcol < slen) {
          int gidx = s0 + lcol;
          #pragma unroll
          for (int e = 0; e < 4; ++e) {
            if (a0[e] >= thrv[0][e]) {
              int q = qbase + w * 32 + g * 4 + e;
              unsigned p = atomicAdd(&cnt[q], 1u);
              if (p < (unsigned)QCAP)
                candq[(size_t)q * QCAP + p] = make_float2(a0[e], __int_as_float(gidx));
            }
            if (a1[e] >= thrv[1][e]) {
              int q = qbase + w * 32 + 16 + g * 4 + e;
              unsigned p = atomicAdd(&cnt[q], 1u);
              if (p < (unsigned)QCAP)
                candq[(size_t)q * QCAP + p] = make_float2(a1[e], __int_as_float(gidx));
            }
          }
        }
      }
    }
    __syncthreads();
    buf ^= 1;
  }
}

// One wave per query: gather ~27 candidates, exact (f64) refine ALL,
// bitonic top-16 (tie: lower idx) -> weights -> out.
__global__ __launch_bounds__(64) void merge_refine_k(
    const float* __restrict__ query, const float* __restrict__ supports,
    const float* __restrict__ targets, const unsigned* __restrict__ cnt,
    const float2* __restrict__ candq, float* __restrict__ out) {
  const int q = blockIdx.x, lane = threadIdx.x;
  __shared__ float qh_s[128];
  __shared__ float2 list[QCAP];
  __shared__ float2 refd[QCAP];

  int total = min((int)cnt[q], QCAP);
  if (lane < total) list[lane] = candq[(size_t)q * QCAP + lane];

  float2 qv = *reinterpret_cast<const float2*>(query + (size_t)q * 128 + lane * 2);
  double qss = (double)qv.x * qv.x + (double)qv.y * qv.y;
  #pragma unroll
  for (int o = 1; o < 64; o <<= 1) qss += __shfl_xor(qss, o);
  float qn1 = fmaxf((float)sqrt(qss), 1e-12f);
  qh_s[lane * 2] = qv.x / qn1;
  qh_s[lane * 2 + 1] = qv.y / qn1;
  __syncthreads();

  const int g16 = lane >> 4, m16 = lane & 15;
  float qh[8];
  #pragma unroll
  for (int d = 0; d < 8; ++d) qh[d] = qh_s[m16 * 8 + d];
  int rounds = (total + 3) >> 2;
  for (int r = 0; r < rounds; ++r) {
    int cc = r * 4 + g16;
    bool valid = cc < total;
    float2 ce = valid ? list[cc] : make_float2(0.f, __int_as_float(0));
    int sidx = __float_as_int(ce.y);
    float4 sa = *reinterpret_cast<const float4*>(supports + (size_t)sidx * 128 + m16 * 8);
    float4 sb = *reinterpret_cast<const float4*>(supports + (size_t)sidx * 128 + m16 * 8 + 4);
    float sv[8] = {sa.x, sa.y, sa.z, sa.w, sb.x, sb.y, sb.z, sb.w};
    double ss = 0.0, dt = 0.0;
    #pragma unroll
    for (int d = 0; d < 8; ++d) {
      ss += (double)sv[d] * sv[d];
      dt += (double)qh[d] * sv[d];
    }
    #pragma unroll
    for (int o = 1; o < 16; o <<= 1) {
      ss += __shfl_xor(ss, o);
      dt += __shfl_xor(dt, o);
    }
    if (m16 == 0 && valid) {
      float sn1 = fmaxf((float)sqrt(ss), 1e-12f);
      refd[cc] = make_float2((float)(1.0 - dt / (double)sn1), ce.y);
    }
  }
  __syncthreads();

  float dv = (lane < total) ? refd[lane].x : 3.0e38f;
  unsigned di = (lane < total) ? (unsigned)__float_as_int(refd[lane].y) : 0xFFFFFFFFu;
  bitonic64(dv, di, lane);  // ascending (d, idx): lanes 0..15 = top-16

  float wv = (lane < 16) ? 1.0f / (dv + 1e-8f) : 0.0f;
  float wsum = wv;
  #pragma unroll
  for (int o = 1; o < 64; o <<= 1) wsum += __shfl_xor(wsum, o);
  float acc[8];
  #pragma unroll
  for (int t = 0; t < 8; ++t) acc[t] = 0.f;
  if (lane < 16) {
    float wn = wv / wsum;
    const float* tp = targets + (size_t)di * 8;
    #pragma unroll
    for (int t = 0; t < 8; ++t) acc[t] = wn * tp[t];
  }
  #pragma unroll
  for (int o = 1; o < 16; o <<= 1) {
    #pragma unroll
    for (int t = 0; t < 8; ++t) acc[t] += __shfl_xor(acc[t], o);
  }
  if (lane == 0) {
    #pragma unroll
    for (int t = 0; t < 8; ++t) out[(size_t)q * 8 + t] = acc[t];
  }
}

extern "C" void kernel_launch(void* const* d_in, const int* in_sizes, int n_in,
                              void* d_out, int out_size, void* d_ws, size_t ws_size,
                              hipStream_t stream) {
  const float* query = (const float*)d_in[0];
  const float* supports = (const float*)d_in[1];
  const float* targets = (const float*)d_in[2];
  float* out = (float*)d_out;
  const int D = 128;
  const int B = in_sizes[0] / D;   // 2048
  const int N = in_sizes[1] / D;   // 100000

  char* ws = (char*)d_ws;
  size_t off = 0;
  ushort* sn = (ushort*)(ws + off); off += (size_t)N * D * 2;
  off = (off + 255) & ~(size_t)255;
  ushort* qn = (ushort*)(ws + off); off += (size_t)B * D * 2;
  off = (off + 255) & ~(size_t)255;
  ushort* cm = (ushort*)(ws + off); off += (size_t)B * NGS * 2;        // 25.7MB
  off = (off + 255) & ~(size_t)255;
  float* thr = (float*)(ws + off); off += (size_t)B * 4;
  off = (off + 255) & ~(size_t)255;
  unsigned* cnt = (unsigned*)(ws + off); off += (size_t)B * 4;
  off = (off + 255) & ~(size_t)255;
  float2* candq = (float2*)(ws + off); off += (size_t)B * QCAP * sizeof(float2);
  if (off > ws_size) return;

  hipMemsetAsync(cnt, 0, (size_t)B * 4, stream);
  hipLaunchKernelGGL(norm_rows_k, dim3((N + 3) / 4), dim3(256), 0, stream, supports, sn, N);
  hipLaunchKernelGGL(norm_rows_k, dim3((B + 3) / 4), dim3(256), 0, stream, query, qn, B);
  int nblk = (B / BQ) * NSLICES;  // 512
  hipLaunchKernelGGL(pass1_k, dim3(nblk), dim3(256), 0, stream, qn, sn, cm, N);
  hipLaunchKernelGGL(thr_k, dim3(B), dim3(64), 0, stream, cm, thr);
  hipLaunchKernelGGL(pass2_k, dim3(nblk), dim3(256), 0, stream, qn, sn, cm, thr, cnt, candq, N);
  hipLaunchKernelGGL(merge_refine_k, dim3(B), dim3(64), 0, stream, query, supports, targets, cnt, candq, out);
}

// Round 8
// 324.289 us; speedup vs baseline: 1.6521x; 1.1552x over previous
//
#include <hip/hip_runtime.h>

// SHGR kNN head: cosine distance, top-16, inverse-distance weighted target average.
// B=2048, N=100000, D=128, T=8, k=16.
//
// Pipeline:
//   1. norm_rows_k: L2-normalize supports & queries -> bf16 (ushort bits) in ws.
//   2. pass1_k: bf16 MFMA; per-(query, 16-col sub-chunk) max -> cm (global, bf16
//      down-rounded, packed [q/4][gs][q%4]).  Grid 1024 = 4 blk/CU (32KB LDS).
//      Pad columns masked to -inf; unwritten tail subs filled with -inf.
//   3. thr_k: thr[q] = (16th-largest of 6400 sub-maxes) - 0.013 margin, via
//      ballot-popcount radix select.  [16th submax <= true 16th score; margin
//      covers bf16 score error (<=2.5e-3 worst case) with 5x slack; tail math:
//      E[cands] = 16*exp(41*margin) ~ 27 per query]
//   4. pass2_k: per (qtile,slice) block: find hit subs (stored max >= thr),
//      batch 4 subs -> staged 64-row tile, recompute scores (bitwise identical
//      MFMA), emit scores >= thr to a per-query global list (cap 64).
//   5. merge_refine_k: per query, exact (f64) refine ALL ~27 candidates,
//      bitonic top-16 -> weights -> gather targets -> out.
//
// NOTE (R7 post-mortem): update_dpp row_ror reduction produced wrong submaxes
// on gfx950 (absmax 0.1 fail); reverted to the proven __shfl_xor reduction.

#define NSLICES 64
#define CN 64
#define BQ 128
#define NSUB 100                 // subs per slice = 25 chunks * 4
#define NGS (NSLICES * NSUB)     // 6400 subs per query
#define QCAP 64                  // per-query candidate list; E=27, P(>64)~1e-9
#define THR_MARGIN 0.013f

typedef __bf16 bf16x8 __attribute__((ext_vector_type(8)));
typedef float f32x4 __attribute__((ext_vector_type(4)));

__device__ __forceinline__ ushort f2bf_rne(float f) {
  unsigned u = __float_as_uint(f);
  return (ushort)((u + 0x7FFFu + ((u >> 16) & 1u)) >> 16);
}
// round toward -inf in bf16 (stored max <= true max)
__device__ __forceinline__ ushort f2bf_down(float f) {
  unsigned u = __float_as_uint(f);
  return (ushort)((u >> 16) + (u >> 31));
}
__device__ __forceinline__ unsigned bf2key(ushort b) {
  return (unsigned)(b ^ ((b & 0x8000u) ? 0xFFFFu : 0x8000u));
}

// Full-wave bitonic sort, ascending in (v, i) lexicographic.
__device__ __forceinline__ void bitonic64(float& v, unsigned& i, int lane) {
  #pragma unroll
  for (int k = 2; k <= 64; k <<= 1) {
    #pragma unroll
    for (int j = k >> 1; j > 0; j >>= 1) {
      float pv = __shfl_xor(v, j);
      unsigned pi = (unsigned)__shfl_xor((int)i, j);
      bool up = ((lane & k) == 0);
      bool lower = ((lane & j) == 0);
      bool gt = (v > pv) || (v == pv && i > pi);
      bool keep = (up == lower) ? !gt : gt;
      if (!keep) { v = pv; i = pi; }
    }
  }
}

__global__ __launch_bounds__(256) void norm_rows_k(const float* __restrict__ x,
                                                   ushort* __restrict__ xb,
                                                   int nrows) {
  int row = blockIdx.x * 4 + (threadIdx.x >> 6);
  int lane = threadIdx.x & 63;
  if (row >= nrows) return;
  float2 v = *reinterpret_cast<const float2*>(x + (size_t)row * 128 + lane * 2);
  float ss = v.x * v.x + v.y * v.y;
  #pragma unroll
  for (int o = 1; o < 64; o <<= 1) ss += __shfl_xor(ss, o);
  float inv = 1.0f / fmaxf(sqrtf(ss), 1e-12f);
  ushort2 h = make_ushort2(f2bf_rne(v.x * inv), f2bf_rne(v.y * inv));
  *reinterpret_cast<ushort2*>(xb + (size_t)row * 128 + lane * 2) = h;
}

// Stage 64x128 bf16 chunk: linear LDS dest + inverse-swizzled global source.
__device__ __forceinline__ void stage_lin(const ushort* __restrict__ sn,
                                          ushort* dst, int cb, int s1, int tid) {
  #pragma unroll
  for (int r = 0; r < 4; ++r) {
    int o = (r << 12) + tid * 16;
    int row = o >> 8;
    int dj = (o >> 4) & 15;
    int sj = dj ^ (row & 7);
    int srow = min(cb + row, s1 - 1);
    __builtin_amdgcn_global_load_lds(
        (const unsigned int*)(sn + (size_t)srow * 128 + sj * 8),
        (unsigned int*)(dst + (o >> 1)), 16, 0, 0);
  }
}

// Stage a gathered batch of 4 sub-chunks (16 rows each) from slist.
__device__ __forceinline__ void stage_list(const ushort* __restrict__ sn,
                                           ushort* dst, const ushort* slist_b,
                                           int s0, int s1, int tid) {
  #pragma unroll
  for (int r = 0; r < 4; ++r) {
    int o = (r << 12) + tid * 16;
    int row = o >> 8;
    int dj = (o >> 4) & 15;
    int sj = dj ^ (row & 7);
    int sub = slist_b[row >> 4];
    int lrow = (sub == 0xFFFF) ? 0 : sub * 16 + (row & 15);
    int srow = min(s0 + lrow, s1 - 1);
    __builtin_amdgcn_global_load_lds(
        (const unsigned int*)(sn + (size_t)srow * 128 + sj * 8),
        (unsigned int*)(dst + (o >> 1)), 16, 0, 0);
  }
}

// Pass 1: sub-chunk maxes. 1024 blocks XCD-decoded (8 slices/XCD, L2-local).
__global__ __launch_bounds__(256, 4) void pass1_k(
    const ushort* __restrict__ qn, const ushort* __restrict__ sn,
    ushort* __restrict__ cm, int N) {
  __shared__ ushort st[2][CN * 128];
  const int tid = threadIdx.x;
  const int w = tid >> 6, lane = tid & 63, g = lane >> 4, m = lane & 15;
  const int L = blockIdx.x;             // 1024 = 8 xcd * (16 qtile * 8 slice)
  const int xcd = L & 7, i6 = L >> 3;
  const int qtile = i6 & 15;
  const int slice = (xcd << 3) | (i6 >> 4);
  const int qbase = qtile * BQ;
  const int SLICE = (N + NSLICES - 1) / NSLICES;  // 1563
  const int s0 = slice * SLICE;
  const int s1 = min(N, s0 + SLICE);
  const int nch = (s1 - s0 + CN - 1) / CN;  // 25 (24 for last slice)

  stage_lin(sn, &st[0][0], s0, s1, tid);

  // A-fragments: k = 32*t + 8*g + e, row = m (same map for B -> permutation cancels)
  bf16x8 afr[2][4];
  #pragma unroll
  for (int sub = 0; sub < 2; ++sub) {
    int qrow = qbase + w * 32 + sub * 16 + m;
    #pragma unroll
    for (int t = 0; t < 4; ++t)
      afr[sub][t] = *reinterpret_cast<const bf16x8*>(qn + (size_t)qrow * 128 + t * 32 + g * 8);
  }
  __syncthreads();

  int buf = 0;
  for (int ch = 0; ch < nch; ++ch) {
    const int cb = s0 + ch * CN;
    if (ch + 1 < nch) stage_lin(sn, &st[buf ^ 1][0], cb + CN, s1, tid);
    const ushort* stc = &st[buf][0];
    #pragma unroll
    for (int ct = 0; ct < 4; ++ct) {
      const int srow = ct * 16 + m;
      f32x4 a0 = {0.f, 0.f, 0.f, 0.f}, a1 = {0.f, 0.f, 0.f, 0.f};
      #pragma unroll
      for (int t = 0; t < 4; ++t) {
        int cj = (4 * t + g) ^ (srow & 7);
        bf16x8 bfr = *reinterpret_cast<const bf16x8*>(&stc[srow * 128 + cj * 8]);
        a0 = __builtin_amdgcn_mfma_f32_16x16x32_bf16(afr[0][t], bfr, a0, 0, 0, 0);
        a1 = __builtin_amdgcn_mfma_f32_16x16x32_bf16(afr[1][t], bfr, a1, 0, 0, 0);
      }
      float m0[4], m1[4];
      #pragma unroll
      for (int e = 0; e < 4; ++e) { m0[e] = a0[e]; m1[e] = a1[e]; }
      // mask pad columns (clamped duplicate rows) to -inf -- last chunk only
      if (ch == nch - 1) {
        bool colok = (cb + ct * 16 + m) < s1;
        #pragma unroll
        for (int e = 0; e < 4; ++e) {
          if (!colok) { m0[e] = -3.0e38f; m1[e] = -3.0e38f; }
        }
      }
      // per-(query, sub) max over the 16 column-lanes (proven shfl_xor reduce)
      #pragma unroll
      for (int o = 1; o < 16; o <<= 1) {
        #pragma unroll
        for (int e = 0; e < 4; ++e) {
          m0[e] = fmaxf(m0[e], __shfl_xor(m0[e], o));
          m1[e] = fmaxf(m1[e], __shfl_xor(m1[e], o));
        }
      }
      if (m == 0) {
        int gs = slice * NSUB + ch * 4 + ct;
        int q0 = qbase + w * 32 + g * 4;       // sub 0 queries (q0..q0+3)
        int q1 = q0 + 16;                      // sub 1
        uint2 p0, p1;
        p0.x = (unsigned)f2bf_down(m0[0]) | ((unsigned)f2bf_down(m0[1]) << 16);
        p0.y = (unsigned)f2bf_down(m0[2]) | ((unsigned)f2bf_down(m0[3]) << 16);
        p1.x = (unsigned)f2bf_down(m1[0]) | ((unsigned)f2bf_down(m1[1]) << 16);
        p1.y = (unsigned)f2bf_down(m1[2]) | ((unsigned)f2bf_down(m1[3]) << 16);
        *reinterpret_cast<uint2*>(cm + ((size_t)(q0 >> 2) * NGS + gs) * 4) = p0;
        *reinterpret_cast<uint2*>(cm + ((size_t)(q1 >> 2) * NGS + gs) * 4) = p1;
      }
    }
    __syncthreads();
    buf ^= 1;
  }

  // fill unwritten tail subs (nch < 25 on the last slice) with bf16 -inf
  const int miss = NSUB - nch * 4;
  for (int idx = tid; idx < miss * BQ; idx += 256) {
    int sub = nch * 4 + idx / BQ;
    int q = qbase + (idx % BQ);
    cm[((size_t)(q >> 2) * NGS + (size_t)(slice * NSUB + sub)) * 4 + (q & 3)] = 0xFF80;
  }
}

// thr[q] = 16th-largest of the 6400 sub-maxes, minus margin. One wave per query.
__global__ __launch_bounds__(64) void thr_k(const ushort* __restrict__ cm,
                                            float* __restrict__ thr) {
  const int q = blockIdx.x, lane = threadIdx.x;
  const size_t base = (size_t)(q >> 2) * NGS * 4 + (q & 3);
  unsigned keys[NGS / 128];
  #pragma unroll
  for (int j = 0; j < NGS / 128; ++j) {
    unsigned k0 = bf2key(cm[base + (size_t)(lane + 128 * j) * 4]);
    unsigned k1 = bf2key(cm[base + (size_t)(lane + 64 + 128 * j) * 4]);
    keys[j] = k0 | (k1 << 16);
  }
  unsigned res = 0;
  for (int b = 15; b >= 0; --b) {
    unsigned t = res | (1u << b);
    int c = 0;
    #pragma unroll
    for (int j = 0; j < NGS / 128; ++j)
      c += (int)((keys[j] & 0xFFFFu) >= t) + (int)((keys[j] >> 16) >= t);
    #pragma unroll
    for (int o = 1; o < 64; o <<= 1) c += __shfl_xor(c, o);
    if (c >= 16) res = t;
  }
  if (lane == 0) {
    ushort b16 = (ushort)((res & 0x8000u) ? (res ^ 0x8000u) : (res ^ 0xFFFFu));
    thr[q] = __uint_as_float((unsigned)b16 << 16) - THR_MARGIN;
  }
}

// Pass 2: visit only hit subs (stored max >= thr), 4 per staged batch.
__global__ __launch_bounds__(256, 4) void pass2_k(
    const ushort* __restrict__ qn, const ushort* __restrict__ sn,
    const ushort* __restrict__ cm, const float* __restrict__ thr,
    unsigned* __restrict__ cnt, float2* __restrict__ candq, int N) {
  __shared__ ushort st[2][CN * 128];
  __shared__ float thr_l[BQ];
  __shared__ unsigned char hit[NSUB];
  __shared__ ushort slist[NSUB + 4];
  __shared__ int nhit_s;

  const int tid = threadIdx.x;
  const int w = tid >> 6, lane = tid & 63, g = lane >> 4, m = lane & 15;
  const int L = blockIdx.x;
  const int xcd = L & 7, i6 = L >> 3;
  const int qtile = i6 & 15;
  const int slice = (xcd << 3) | (i6 >> 4);
  const int qbase = qtile * BQ;
  const int SLICE = (N + NSLICES - 1) / NSLICES;
  const int s0 = slice * SLICE;
  const int s1 = min(N, s0 + SLICE);
  const int slen = s1 - s0;

  if (tid < BQ) thr_l[tid] = thr[qbase + tid];
  if (tid < NSUB) hit[tid] = 0;
  __syncthreads();

  // hit scan: thread (q = tid&127, parity = tid>>7) covers s = 2j+parity
  {
    int q = qbase + (tid & 127);
    int sh = tid >> 7;
    float tq = thr_l[tid & 127];
    size_t base = (size_t)(q >> 2) * NGS * 4 + (q & 3);
    for (int j = 0; j < NSUB / 2; ++j) {
      int s = 2 * j + sh;
      ushort b = cm[base + (size_t)(slice * NSUB + s) * 4];
      if (__uint_as_float((unsigned)b << 16) >= tq) hit[s] = 1;
    }
  }
  __syncthreads();
  // compact hit subs (wave 0)
  if (tid < 64) {
    int total = 0;
    #pragma unroll
    for (int r = 0; r < 2; ++r) {
      int idx = r * 64 + tid;
      bool f = (idx < NSUB) && hit[idx];
      unsigned long long bm = __ballot(f);
      int pos = total + __popcll(bm & ((1ull << tid) - 1ull));
      if (f) slist[pos] = (ushort)idx;
      total += __popcll(bm);
    }
    if (tid == 0) {
      nhit_s = total;
      #pragma unroll
      for (int p = 0; p < 4; ++p) slist[total + p] = 0xFFFF;
    }
  }
  __syncthreads();
  const int nhit = nhit_s;
  if (nhit == 0) return;
  const int nb = (nhit + 3) >> 2;

  bf16x8 afr[2][4];
  #pragma unroll
  for (int sub = 0; sub < 2; ++sub) {
    int qrow = qbase + w * 32 + sub * 16 + m;
    #pragma unroll
    for (int t = 0; t < 4; ++t)
      afr[sub][t] = *reinterpret_cast<const bf16x8*>(qn + (size_t)qrow * 128 + t * 32 + g * 8);
  }
  float thrv[2][4];
  #pragma unroll
  for (int sub = 0; sub < 2; ++sub)
    #pragma unroll
    for (int e = 0; e < 4; ++e)
      thrv[sub][e] = thr_l[w * 32 + sub * 16 + g * 4 + e];

  stage_list(sn, &st[0][0], &slist[0], s0, s1, tid);
  __syncthreads();

  int buf = 0;
  for (int b = 0; b < nb; ++b) {
    if (b + 1 < nb) stage_list(sn, &st[buf ^ 1][0], &slist[(b + 1) * 4], s0, s1, tid);
    const ushort* stc = &st[buf][0];
    #pragma unroll
    for (int ct = 0; ct < 4; ++ct) {
      const int srow = ct * 16 + m;
      f32x4 a0 = {0.f, 0.f, 0.f, 0.f}, a1 = {0.f, 0.f, 0.f, 0.f};
      #pragma unroll
      for (int t = 0; t < 4; ++t) {
        int cj = (4 * t + g) ^ (srow & 7);
        bf16x8 bfr = *reinterpret_cast<const bf16x8*>(&stc[srow * 128 + cj * 8]);
        a0 = __builtin_amdgcn_mfma_f32_16x16x32_bf16(afr[0][t], bfr, a0, 0, 0, 0);
        a1 = __builtin_amdgcn_mfma_f32_16x16x32_bf16(afr[1][t], bfr, a1, 0, 0, 0);
      }
      int sub = slist[b * 4 + ct];
      if (sub != 0xFFFF) {
        int lcol = sub * 16 + m;       // slice-local support index of this column
        if (lcol < slen) {
          int gidx = s0 + lcol;
          #pragma unroll
          for (int e = 0; e < 4; ++e) {
            if (a0[e] >= thrv[0][e]) {
              int q = qbase + w * 32 + g * 4 + e;
              unsigned p = atomicAdd(&cnt[q], 1u);
              if (p < (unsigned)QCAP)
                candq[(size_t)q * QCAP + p] = make_float2(a0[e], __int_as_float(gidx));
            }
            if (a1[e] >= thrv[1][e]) {
              int q = qbase + w * 32 + 16 + g * 4 + e;
              unsigned p = atomicAdd(&cnt[q], 1u);
              if (p < (unsigned)QCAP)
                candq[(size_t)q * QCAP + p] = make_float2(a1[e], __int_as_float(gidx));
            }
          }
        }
      }
    }
    __syncthreads();
    buf ^= 1;
  }
}

// One wave per query: gather ~27 candidates, exact (f64) refine ALL,
// bitonic top-16 (tie: lower idx) -> weights -> out.
__global__ __launch_bounds__(64) void merge_refine_k(
    const float* __restrict__ query, const float* __restrict__ supports,
    const float* __restrict__ targets, const unsigned* __restrict__ cnt,
    const float2* __restrict__ candq, float* __restrict__ out) {
  const int q = blockIdx.x, lane = threadIdx.x;
  __shared__ float qh_s[128];
  __shared__ float2 list[QCAP];
  __shared__ float2 refd[QCAP];

  int total = min((int)cnt[q], QCAP);
  if (lane < total) list[lane] = candq[(size_t)q * QCAP + lane];

  float2 qv = *reinterpret_cast<const float2*>(query + (size_t)q * 128 + lane * 2);
  double qss = (double)qv.x * qv.x + (double)qv.y * qv.y;
  #pragma unroll
  for (int o = 1; o < 64; o <<= 1) qss += __shfl_xor(qss, o);
  float qn1 = fmaxf((float)sqrt(qss), 1e-12f);
  qh_s[lane * 2] = qv.x / qn1;
  qh_s[lane * 2 + 1] = qv.y / qn1;
  __syncthreads();

  const int g16 = lane >> 4, m16 = lane & 15;
  float qh[8];
  #pragma unroll
  for (int d = 0; d < 8; ++d) qh[d] = qh_s[m16 * 8 + d];
  int rounds = (total + 3) >> 2;
  for (int r = 0; r < rounds; ++r) {
    int cc = r * 4 + g16;
    bool valid = cc < total;
    float2 ce = valid ? list[cc] : make_float2(0.f, __int_as_float(0));
    int sidx = __float_as_int(ce.y);
    float4 sa = *reinterpret_cast<const float4*>(supports + (size_t)sidx * 128 + m16 * 8);
    float4 sb = *reinterpret_cast<const float4*>(supports + (size_t)sidx * 128 + m16 * 8 + 4);
    float sv[8] = {sa.x, sa.y, sa.z, sa.w, sb.x, sb.y, sb.z, sb.w};
    double ss = 0.0, dt = 0.0;
    #pragma unroll
    for (int d = 0; d < 8; ++d) {
      ss += (double)sv[d] * sv[d];
      dt += (double)qh[d] * sv[d];
    }
    #pragma unroll
    for (int o = 1; o < 16; o <<= 1) {
      ss += __shfl_xor(ss, o);
      dt += __shfl_xor(dt, o);
    }
    if (m16 == 0 && valid) {
      float sn1 = fmaxf((float)sqrt(ss), 1e-12f);
      refd[cc] = make_float2((float)(1.0 - dt / (double)sn1), ce.y);
    }
  }
  __syncthreads();

  float dv = (lane < total) ? refd[lane].x : 3.0e38f;
  unsigned di = (lane < total) ? (unsigned)__float_as_int(refd[lane].y) : 0xFFFFFFFFu;
  bitonic64(dv, di, lane);  // ascending (d, idx): lanes 0..15 = top-16

  float wv = (lane < 16) ? 1.0f / (dv + 1e-8f) : 0.0f;
  float wsum = wv;
  #pragma unroll
  for (int o = 1; o < 64; o <<= 1) wsum += __shfl_xor(wsum, o);
  float acc[8];
  #pragma unroll
  for (int t = 0; t < 8; ++t) acc[t] = 0.f;
  if (lane < 16) {
    float wn = wv / wsum;
    const float* tp = targets + (size_t)di * 8;
    #pragma unroll
    for (int t = 0; t < 8; ++t) acc[t] = wn * tp[t];
  }
  #pragma unroll
  for (int o = 1; o < 16; o <<= 1) {
    #pragma unroll
    for (int t = 0; t < 8; ++t) acc[t] += __shfl_xor(acc[t], o);
  }
  if (lane == 0) {
    #pragma unroll
    for (int t = 0; t < 8; ++t) out[(size_t)q * 8 + t] = acc[t];
  }
}

extern "C" void kernel_launch(void* const* d_in, const int* in_sizes, int n_in,
                              void* d_out, int out_size, void* d_ws, size_t ws_size,
                              hipStream_t stream) {
  const float* query = (const float*)d_in[0];
  const float* supports = (const float*)d_in[1];
  const float* targets = (const float*)d_in[2];
  float* out = (float*)d_out;
  const int D = 128;
  const int B = in_sizes[0] / D;   // 2048
  const int N = in_sizes[1] / D;   // 100000

  char* ws = (char*)d_ws;
  size_t off = 0;
  ushort* sn = (ushort*)(ws + off); off += (size_t)N * D * 2;
  off = (off + 255) & ~(size_t)255;
  ushort* qn = (ushort*)(ws + off); off += (size_t)B * D * 2;
  off = (off + 255) & ~(size_t)255;
  ushort* cm = (ushort*)(ws + off); off += (size_t)B * NGS * 2;        // 26.2MB
  off = (off + 255) & ~(size_t)255;
  float* thr = (float*)(ws + off); off += (size_t)B * 4;
  off = (off + 255) & ~(size_t)255;
  unsigned* cnt = (unsigned*)(ws + off); off += (size_t)B * 4;
  off = (off + 255) & ~(size_t)255;
  float2* candq = (float2*)(ws + off); off += (size_t)B * QCAP * sizeof(float2);
  if (off > ws_size) return;

  hipMemsetAsync(cnt, 0, (size_t)B * 4, stream);
  hipLaunchKernelGGL(norm_rows_k, dim3((N + 3) / 4), dim3(256), 0, stream, supports, sn, N);
  hipLaunchKernelGGL(norm_rows_k, dim3((B + 3) / 4), dim3(256), 0, stream, query, qn, B);
  int nblk = (B / BQ) * NSLICES;  // 1024
  hipLaunchKernelGGL(pass1_k, dim3(nblk), dim3(256), 0, stream, qn, sn, cm, N);
  hipLaunchKernelGGL(thr_k, dim3(B), dim3(64), 0, stream, cm, thr);
  hipLaunchKernelGGL(pass2_k, dim3(nblk), dim3(256), 0, stream, qn, sn, cm, thr, cnt, candq, N);
  hipLaunchKernelGGL(merge_refine_k, dim3(B), dim3(64), 0, stream, query, supports, targets, cnt, candq, out);
}

// Round 9
// 209.471 us; speedup vs baseline: 2.5577x; 1.5481x over previous
//
#include <hip/hip_runtime.h>

// SHGR kNN head: cosine distance, top-16, inverse-distance weighted target average.
// B=2048, N=100000, D=128, T=8, k=16.
//
// Pipeline:
//   1. norm_rows_k: L2-normalize supports & queries -> bf16 (ushort bits) in ws.
//   2. pass1_k: bf16 MFMA (TRANSPOSED: D[support][query] so the 16-support sub
//      reduction is 3 in-reg fmax + 2 shfl, not 4 shfl per value); per-(query,
//      16-col sub) max -> cm (global, bf16 down-rounded, packed [q/4][gs][q%4]).
//   3. thr_k: thr[q] = (16th-largest of 6400 sub-maxes) - 0.013 margin.
//      [16th submax <= true 16th score; margin covers bf16 score error
//      (<=2.5e-3 worst case) with 5x slack; E[cands] = 16*exp(41*margin) ~ 27]
//   4. pass2_k: per (qtile,slice) block: find hit subs (stored max >= thr),
//      batch 4 subs -> staged 64-row tile, recompute scores (transposed MFMA),
//      emit scores >= thr to a per-query global list (cap 64).
//   5. merge_refine_k: per query, exact (f64) refine ALL ~27 candidates,
//      bitonic top-16 -> weights -> gather targets -> out.
//
// NOTE (R7): update_dpp row_ror gave wrong submaxes on gfx950 -> shfl_xor only.

#define NSLICES 64
#define CN 64
#define BQ 128
#define NSUB 100                 // subs per slice = 25 chunks * 4
#define NGS (NSLICES * NSUB)     // 6400 subs per query
#define QCAP 64                  // per-query candidate list; E=27, P(>64)~1e-9
#define THR_MARGIN 0.013f

typedef __bf16 bf16x8 __attribute__((ext_vector_type(8)));
typedef float f32x4 __attribute__((ext_vector_type(4)));

__device__ __forceinline__ ushort f2bf_rne(float f) {
  unsigned u = __float_as_uint(f);
  return (ushort)((u + 0x7FFFu + ((u >> 16) & 1u)) >> 16);
}
// round toward -inf in bf16 (stored max <= true max)
__device__ __forceinline__ ushort f2bf_down(float f) {
  unsigned u = __float_as_uint(f);
  return (ushort)((u >> 16) + (u >> 31));
}
__device__ __forceinline__ unsigned bf2key(ushort b) {
  return (unsigned)(b ^ ((b & 0x8000u) ? 0xFFFFu : 0x8000u));
}

// Full-wave bitonic sort, ascending in (v, i) lexicographic.
__device__ __forceinline__ void bitonic64(float& v, unsigned& i, int lane) {
  #pragma unroll
  for (int k = 2; k <= 64; k <<= 1) {
    #pragma unroll
    for (int j = k >> 1; j > 0; j >>= 1) {
      float pv = __shfl_xor(v, j);
      unsigned pi = (unsigned)__shfl_xor((int)i, j);
      bool up = ((lane & k) == 0);
      bool lower = ((lane & j) == 0);
      bool gt = (v > pv) || (v == pv && i > pi);
      bool keep = (up == lower) ? !gt : gt;
      if (!keep) { v = pv; i = pi; }
    }
  }
}

__global__ __launch_bounds__(256) void norm_rows_k(const float* __restrict__ x,
                                                   ushort* __restrict__ xb,
                                                   int nrows) {
  int row = blockIdx.x * 4 + (threadIdx.x >> 6);
  int lane = threadIdx.x & 63;
  if (row >= nrows) return;
  float2 v = *reinterpret_cast<const float2*>(x + (size_t)row * 128 + lane * 2);
  float ss = v.x * v.x + v.y * v.y;
  #pragma unroll
  for (int o = 1; o < 64; o <<= 1) ss += __shfl_xor(ss, o);
  float inv = 1.0f / fmaxf(sqrtf(ss), 1e-12f);
  ushort2 h = make_ushort2(f2bf_rne(v.x * inv), f2bf_rne(v.y * inv));
  *reinterpret_cast<ushort2*>(xb + (size_t)row * 128 + lane * 2) = h;
}

// Stage 64x128 bf16 chunk: linear LDS dest + inverse-swizzled global source.
__device__ __forceinline__ void stage_lin(const ushort* __restrict__ sn,
                                          ushort* dst, int cb, int s1, int tid) {
  #pragma unroll
  for (int r = 0; r < 4; ++r) {
    int o = (r << 12) + tid * 16;
    int row = o >> 8;
    int dj = (o >> 4) & 15;
    int sj = dj ^ (row & 7);
    int srow = min(cb + row, s1 - 1);
    __builtin_amdgcn_global_load_lds(
        (const unsigned int*)(sn + (size_t)srow * 128 + sj * 8),
        (unsigned int*)(dst + (o >> 1)), 16, 0, 0);
  }
}

// Stage a gathered batch of 4 sub-chunks (16 rows each) from slist.
__device__ __forceinline__ void stage_list(const ushort* __restrict__ sn,
                                           ushort* dst, const ushort* slist_b,
                                           int s0, int s1, int tid) {
  #pragma unroll
  for (int r = 0; r < 4; ++r) {
    int o = (r << 12) + tid * 16;
    int row = o >> 8;
    int dj = (o >> 4) & 15;
    int sj = dj ^ (row & 7);
    int sub = slist_b[row >> 4];
    int lrow = (sub == 0xFFFF) ? 0 : sub * 16 + (row & 15);
    int srow = min(s0 + lrow, s1 - 1);
    __builtin_amdgcn_global_load_lds(
        (const unsigned int*)(sn + (size_t)srow * 128 + sj * 8),
        (unsigned int*)(dst + (o >> 1)), 16, 0, 0);
  }
}

// Pass 1: sub-chunk maxes. 1024 blocks XCD-decoded (8 slices/XCD, L2-local).
// Transposed MFMA: D[row=support][col=query]; lane holds 4 supports x 1 query.
__global__ __launch_bounds__(256, 4) void pass1_k(
    const ushort* __restrict__ qn, const ushort* __restrict__ sn,
    ushort* __restrict__ cm, int N) {
  __shared__ ushort st[2][CN * 128];
  const int tid = threadIdx.x;
  const int w = tid >> 6, lane = tid & 63, g = lane >> 4, m = lane & 15;
  const int L = blockIdx.x;             // 1024 = 8 xcd * (16 qtile * 8 slice)
  const int xcd = L & 7, i6 = L >> 3;
  const int qtile = i6 & 15;
  const int slice = (xcd << 3) | (i6 >> 4);
  const int qbase = qtile * BQ;
  const int SLICE = (N + NSLICES - 1) / NSLICES;  // 1563
  const int s0 = slice * SLICE;
  const int s1 = min(N, s0 + SLICE);
  const int nch = (s1 - s0 + CN - 1) / CN;  // 25 (24 for last slice)

  stage_lin(sn, &st[0][0], s0, s1, tid);

  // Query fragments (B operand): k = 32*t + 8*g + e, col = m.
  bf16x8 afr[2][4];
  #pragma unroll
  for (int jt = 0; jt < 2; ++jt) {
    int qrow = qbase + w * 32 + jt * 16 + m;
    #pragma unroll
    for (int t = 0; t < 4; ++t)
      afr[jt][t] = *reinterpret_cast<const bf16x8*>(qn + (size_t)qrow * 128 + t * 32 + g * 8);
  }
  __syncthreads();

  int buf = 0;
  for (int ch = 0; ch < nch; ++ch) {
    const int cb = s0 + ch * CN;
    if (ch + 1 < nch) stage_lin(sn, &st[buf ^ 1][0], cb + CN, s1, tid);
    const ushort* stc = &st[buf][0];
    const bool lastch = (ch == nch - 1);
    #pragma unroll
    for (int ct = 0; ct < 4; ++ct) {
      const int srow = ct * 16 + m;     // A-operand row = support (lane m)
      f32x4 a0 = {0.f, 0.f, 0.f, 0.f}, a1 = {0.f, 0.f, 0.f, 0.f};
      #pragma unroll
      for (int t = 0; t < 4; ++t) {
        int cj = (4 * t + g) ^ (srow & 7);
        bf16x8 sfr = *reinterpret_cast<const bf16x8*>(&stc[srow * 128 + cj * 8]);
        a0 = __builtin_amdgcn_mfma_f32_16x16x32_bf16(sfr, afr[0][t], a0, 0, 0, 0);
        a1 = __builtin_amdgcn_mfma_f32_16x16x32_bf16(sfr, afr[1][t], a1, 0, 0, 0);
      }
      // mask invalid supports (D rows: support = cb + ct*16 + g*4 + e)
      if (lastch) {
        int si = cb + ct * 16 + g * 4;
        #pragma unroll
        for (int e = 0; e < 4; ++e) {
          if (si + e >= s1) { a0[e] = -3.0e38f; a1[e] = -3.0e38f; }
        }
      }
      // in-register max over 4 supports, then across the 4 g-groups
      float v0 = fmaxf(fmaxf(a0[0], a0[1]), fmaxf(a0[2], a0[3]));
      float v1 = fmaxf(fmaxf(a1[0], a1[1]), fmaxf(a1[2], a1[3]));
      v0 = fmaxf(v0, __shfl_xor(v0, 16));
      v0 = fmaxf(v0, __shfl_xor(v0, 32));
      v1 = fmaxf(v1, __shfl_xor(v1, 16));
      v1 = fmaxf(v1, __shfl_xor(v1, 32));
      // pack 4 queries' bf16 submaxes -> 8B store on lanes (g==0, m%4==0)
      unsigned u0 = (unsigned)f2bf_down(v0);
      unsigned u1 = (unsigned)f2bf_down(v1);
      unsigned w0 = u0 | ((unsigned)__shfl_xor((int)u0, 1) << 16);
      unsigned w1 = u1 | ((unsigned)__shfl_xor((int)u1, 1) << 16);
      unsigned x0 = (unsigned)__shfl_xor((int)w0, 2);
      unsigned x1 = (unsigned)__shfl_xor((int)w1, 2);
      if (g == 0 && (m & 3) == 0) {
        int gs = slice * NSUB + ch * 4 + ct;
        int q0 = qbase + w * 32 + m;       // jt=0 queries q0..q0+3 (q0%4==0)
        int q1 = q0 + 16;                  // jt=1
        *reinterpret_cast<uint2*>(cm + ((size_t)(q0 >> 2) * NGS + gs) * 4) =
            make_uint2(w0, x0);
        *reinterpret_cast<uint2*>(cm + ((size_t)(q1 >> 2) * NGS + gs) * 4) =
            make_uint2(w1, x1);
      }
    }
    __syncthreads();
    buf ^= 1;
  }

  // fill unwritten tail subs (nch < 25 on the last slice) with bf16 -inf
  const int miss = NSUB - nch * 4;
  for (int idx = tid; idx < miss * BQ; idx += 256) {
    int sub = nch * 4 + idx / BQ;
    int q = qbase + (idx % BQ);
    cm[((size_t)(q >> 2) * NGS + (size_t)(slice * NSUB + sub)) * 4 + (q & 3)] = 0xFF80;
  }
}

// thr[q] = 16th-largest of the 6400 sub-maxes, minus margin. One wave per query.
__global__ __launch_bounds__(64) void thr_k(const ushort* __restrict__ cm,
                                            float* __restrict__ thr) {
  const int q = blockIdx.x, lane = threadIdx.x;
  const size_t base = (size_t)(q >> 2) * NGS * 4 + (q & 3);
  unsigned keys[NGS / 128];
  #pragma unroll
  for (int j = 0; j < NGS / 128; ++j) {
    unsigned k0 = bf2key(cm[base + (size_t)(lane + 128 * j) * 4]);
    unsigned k1 = bf2key(cm[base + (size_t)(lane + 64 + 128 * j) * 4]);
    keys[j] = k0 | (k1 << 16);
  }
  unsigned res = 0;
  for (int b = 15; b >= 0; --b) {
    unsigned t = res | (1u << b);
    int c = 0;
    #pragma unroll
    for (int j = 0; j < NGS / 128; ++j)
      c += (int)((keys[j] & 0xFFFFu) >= t) + (int)((keys[j] >> 16) >= t);
    #pragma unroll
    for (int o = 1; o < 64; o <<= 1) c += __shfl_xor(c, o);
    if (c >= 16) res = t;
  }
  if (lane == 0) {
    ushort b16 = (ushort)((res & 0x8000u) ? (res ^ 0x8000u) : (res ^ 0xFFFFu));
    thr[q] = __uint_as_float((unsigned)b16 << 16) - THR_MARGIN;
  }
}

// Pass 2: visit only hit subs (stored max >= thr), 4 per staged batch.
// Transposed MFMA: lane holds 4 supports x 1 query; thr per lane hoisted.
__global__ __launch_bounds__(256, 4) void pass2_k(
    const ushort* __restrict__ qn, const ushort* __restrict__ sn,
    const ushort* __restrict__ cm, const float* __restrict__ thr,
    unsigned* __restrict__ cnt, float2* __restrict__ candq, int N) {
  __shared__ ushort st[2][CN * 128];
  __shared__ float thr_l[BQ];
  __shared__ unsigned char hit[NSUB];
  __shared__ ushort slist[NSUB + 4];
  __shared__ int nhit_s;

  const int tid = threadIdx.x;
  const int w = tid >> 6, lane = tid & 63, g = lane >> 4, m = lane & 15;
  const int L = blockIdx.x;
  const int xcd = L & 7, i6 = L >> 3;
  const int qtile = i6 & 15;
  const int slice = (xcd << 3) | (i6 >> 4);
  const int qbase = qtile * BQ;
  const int SLICE = (N + NSLICES - 1) / NSLICES;
  const int s0 = slice * SLICE;
  const int s1 = min(N, s0 + SLICE);
  const int slen = s1 - s0;

  if (tid < BQ) thr_l[tid] = thr[qbase + tid];
  if (tid < NSUB) hit[tid] = 0;
  __syncthreads();

  // hit scan: thread (q = tid&127, parity = tid>>7) covers s = 2j+parity
  {
    int q = qbase + (tid & 127);
    int sh = tid >> 7;
    float tq = thr_l[tid & 127];
    size_t base = (size_t)(q >> 2) * NGS * 4 + (q & 3);
    for (int j = 0; j < NSUB / 2; ++j) {
      int s = 2 * j + sh;
      ushort b = cm[base + (size_t)(slice * NSUB + s) * 4];
      if (__uint_as_float((unsigned)b << 16) >= tq) hit[s] = 1;
    }
  }
  __syncthreads();
  // compact hit subs (wave 0)
  if (tid < 64) {
    int total = 0;
    #pragma unroll
    for (int r = 0; r < 2; ++r) {
      int idx = r * 64 + tid;
      bool f = (idx < NSUB) && hit[idx];
      unsigned long long bm = __ballot(f);
      int pos = total + __popcll(bm & ((1ull << tid) - 1ull));
      if (f) slist[pos] = (ushort)idx;
      total += __popcll(bm);
    }
    if (tid == 0) {
      nhit_s = total;
      #pragma unroll
      for (int p = 0; p < 4; ++p) slist[total + p] = 0xFFFF;
    }
  }
  __syncthreads();
  const int nhit = nhit_s;
  if (nhit == 0) return;
  const int nb = (nhit + 3) >> 2;

  bf16x8 afr[2][4];
  #pragma unroll
  for (int jt = 0; jt < 2; ++jt) {
    int qrow = qbase + w * 32 + jt * 16 + m;
    #pragma unroll
    for (int t = 0; t < 4; ++t)
      afr[jt][t] = *reinterpret_cast<const bf16x8*>(qn + (size_t)qrow * 128 + t * 32 + g * 8);
  }
  const float thrq0 = thr_l[w * 32 + m];        // query of jt=0 (lane m)
  const float thrq1 = thr_l[w * 32 + 16 + m];   // query of jt=1

  stage_list(sn, &st[0][0], &slist[0], s0, s1, tid);
  __syncthreads();

  int buf = 0;
  for (int b = 0; b < nb; ++b) {
    if (b + 1 < nb) stage_list(sn, &st[buf ^ 1][0], &slist[(b + 1) * 4], s0, s1, tid);
    const ushort* stc = &st[buf][0];
    #pragma unroll
    for (int ct = 0; ct < 4; ++ct) {
      const int srow = ct * 16 + m;
      f32x4 a0 = {0.f, 0.f, 0.f, 0.f}, a1 = {0.f, 0.f, 0.f, 0.f};
      #pragma unroll
      for (int t = 0; t < 4; ++t) {
        int cj = (4 * t + g) ^ (srow & 7);
        bf16x8 sfr = *reinterpret_cast<const bf16x8*>(&stc[srow * 128 + cj * 8]);
        a0 = __builtin_amdgcn_mfma_f32_16x16x32_bf16(sfr, afr[0][t], a0, 0, 0, 0);
        a1 = __builtin_amdgcn_mfma_f32_16x16x32_bf16(sfr, afr[1][t], a1, 0, 0, 0);
      }
      int sub = slist[b * 4 + ct];
      if (sub != 0xFFFF) {
        int li0 = sub * 16 + g * 4;    // slice-local support of e=0 (D row)
        bool h0[4], h1[4];
        bool any = false;
        #pragma unroll
        for (int e = 0; e < 4; ++e) {
          bool ok = (li0 + e) < slen;
          h0[e] = ok && (a0[e] >= thrq0);
          h1[e] = ok && (a1[e] >= thrq1);
          any = any || h0[e] || h1[e];
        }
        if (__any(any)) {
          #pragma unroll
          for (int e = 0; e < 4; ++e) {
            if (h0[e]) {
              int q = qbase + w * 32 + m;
              unsigned p = atomicAdd(&cnt[q], 1u);
              if (p < (unsigned)QCAP)
                candq[(size_t)q * QCAP + p] =
                    make_float2(a0[e], __int_as_float(s0 + li0 + e));
            }
            if (h1[e]) {
              int q = qbase + w * 32 + 16 + m;
              unsigned p = atomicAdd(&cnt[q], 1u);
              if (p < (unsigned)QCAP)
                candq[(size_t)q * QCAP + p] =
                    make_float2(a1[e], __int_as_float(s0 + li0 + e));
            }
          }
        }
      }
    }
    __syncthreads();
    buf ^= 1;
  }
}

// One wave per query: gather ~27 candidates, exact (f64) refine ALL,
// bitonic top-16 (tie: lower idx) -> weights -> out.
__global__ __launch_bounds__(64) void merge_refine_k(
    const float* __restrict__ query, const float* __restrict__ supports,
    const float* __restrict__ targets, const unsigned* __restrict__ cnt,
    const float2* __restrict__ candq, float* __restrict__ out) {
  const int q = blockIdx.x, lane = threadIdx.x;
  __shared__ float qh_s[128];
  __shared__ float2 list[QCAP];
  __shared__ float2 refd[QCAP];

  int total = min((int)cnt[q], QCAP);
  if (lane < total) list[lane] = candq[(size_t)q * QCAP + lane];

  float2 qv = *reinterpret_cast<const float2*>(query + (size_t)q * 128 + lane * 2);
  double qss = (double)qv.x * qv.x + (double)qv.y * qv.y;
  #pragma unroll
  for (int o = 1; o < 64; o <<= 1) qss += __shfl_xor(qss, o);
  float qn1 = fmaxf((float)sqrt(qss), 1e-12f);
  qh_s[lane * 2] = qv.x / qn1;
  qh_s[lane * 2 + 1] = qv.y / qn1;
  __syncthreads();

  const int g16 = lane >> 4, m16 = lane & 15;
  float qh[8];
  #pragma unroll
  for (int d = 0; d < 8; ++d) qh[d] = qh_s[m16 * 8 + d];
  int rounds = (total + 3) >> 2;
  for (int r = 0; r < rounds; ++r) {
    int cc = r * 4 + g16;
    bool valid = cc < total;
    float2 ce = valid ? list[cc] : make_float2(0.f, __int_as_float(0));
    int sidx = __float_as_int(ce.y);
    float4 sa = *reinterpret_cast<const float4*>(supports + (size_t)sidx * 128 + m16 * 8);
    float4 sb = *reinterpret_cast<const float4*>(supports + (size_t)sidx * 128 + m16 * 8 + 4);
    float sv[8] = {sa.x, sa.y, sa.z, sa.w, sb.x, sb.y, sb.z, sb.w};
    double ss = 0.0, dt = 0.0;
    #pragma unroll
    for (int d = 0; d < 8; ++d) {
      ss += (double)sv[d] * sv[d];
      dt += (double)qh[d] * sv[d];
    }
    #pragma unroll
    for (int o = 1; o < 16; o <<= 1) {
      ss += __shfl_xor(ss, o);
      dt += __shfl_xor(dt, o);
    }
    if (m16 == 0 && valid) {
      float sn1 = fmaxf((float)sqrt(ss), 1e-12f);
      refd[cc] = make_float2((float)(1.0 - dt / (double)sn1), ce.y);
    }
  }
  __syncthreads();

  float dv = (lane < total) ? refd[lane].x : 3.0e38f;
  unsigned di = (lane < total) ? (unsigned)__float_as_int(refd[lane].y) : 0xFFFFFFFFu;
  bitonic64(dv, di, lane);  // ascending (d, idx): lanes 0..15 = top-16

  float wv = (lane < 16) ? 1.0f / (dv + 1e-8f) : 0.0f;
  float wsum = wv;
  #pragma unroll
  for (int o = 1; o < 64; o <<= 1) wsum += __shfl_xor(wsum, o);
  float acc[8];
  #pragma unroll
  for (int t = 0; t < 8; ++t) acc[t] = 0.f;
  if (lane < 16) {
    float wn = wv / wsum;
    const float* tp = targets + (size_t)di * 8;
    #pragma unroll
    for (int t = 0; t < 8; ++t) acc[t] = wn * tp[t];
  }
  #pragma unroll
  for (int o = 1; o < 16; o <<= 1) {
    #pragma unroll
    for (int t = 0; t < 8; ++t) acc[t] += __shfl_xor(acc[t], o);
  }
  if (lane == 0) {
    #pragma unroll
    for (int t = 0; t < 8; ++t) out[(size_t)q * 8 + t] = acc[t];
  }
}

extern "C" void kernel_launch(void* const* d_in, const int* in_sizes, int n_in,
                              void* d_out, int out_size, void* d_ws, size_t ws_size,
                              hipStream_t stream) {
  const float* query = (const float*)d_in[0];
  const float* supports = (const float*)d_in[1];
  const float* targets = (const float*)d_in[2];
  float* out = (float*)d_out;
  const int D = 128;
  const int B = in_sizes[0] / D;   // 2048
  const int N = in_sizes[1] / D;   // 100000

  char* ws = (char*)d_ws;
  size_t off = 0;
  ushort* sn = (ushort*)(ws + off); off += (size_t)N * D * 2;
  off = (off + 255) & ~(size_t)255;
  ushort* qn = (ushort*)(ws + off); off += (size_t)B * D * 2;
  off = (off + 255) & ~(size_t)255;
  ushort* cm = (ushort*)(ws + off); off += (size_t)B * NGS * 2;        // 26.2MB
  off = (off + 255) & ~(size_t)255;
  float* thr = (float*)(ws + off); off += (size_t)B * 4;
  off = (off + 255) & ~(size_t)255;
  unsigned* cnt = (unsigned*)(ws + off); off += (size_t)B * 4;
  off = (off + 255) & ~(size_t)255;
  float2* candq = (float2*)(ws + off); off += (size_t)B * QCAP * sizeof(float2);
  if (off > ws_size) return;

  hipMemsetAsync(cnt, 0, (size_t)B * 4, stream);
  hipLaunchKernelGGL(norm_rows_k, dim3((N + 3) / 4), dim3(256), 0, stream, supports, sn, N);
  hipLaunchKernelGGL(norm_rows_k, dim3((B + 3) / 4), dim3(256), 0, stream, query, qn, B);
  int nblk = (B / BQ) * NSLICES;  // 1024
  hipLaunchKernelGGL(pass1_k, dim3(nblk), dim3(256), 0, stream, qn, sn, cm, N);
  hipLaunchKernelGGL(thr_k, dim3(B), dim3(64), 0, stream, cm, thr);
  hipLaunchKernelGGL(pass2_k, dim3(nblk), dim3(256), 0, stream, qn, sn, cm, thr, cnt, candq, N);
  hipLaunchKernelGGL(merge_refine_k, dim3(B), dim3(64), 0, stream, query, supports, targets, cnt, candq, out);
}